// Round 16
// baseline (140.424 us; speedup 1.0000x reference)
//
#include <hip/hip_runtime.h>
#include <hip/hip_bf16.h>
#include <math.h>

#define NPIX 4096
#define CH   256

// ---- ws float offsets ----
#define OFF_XP    0u         // bf16 packed x; later convp f32 [8][1024][256] (spans XP+XR)
#define OFF_XR    1048576u   // (free; convp upper half)
#define OFF_VB    2097152u   // bf16 v [2][4096][256] (BN input)
#define OFF_TBS   3145728u   // bf16 swizzled y^T; later xdtb pack
#define OFF_TBS2  4194304u   // bf16 swizzled E^T; later xpp conv input pack
#define OFF_HG    5242880u   // uint32 [2][4096][128] incidence bitmask
#define OFF_SQ    6291456u   // [8192] f32
#define OFF_PART  6299648u   // [512 blk][128] f32 BN partials (64 sum + 64 ss)
#define OFF_BNSS  6365184u   // [512] f32
#define OFF_DINV  6365696u   // [8192] f32 1/deg
#define OFF_W3P   6373888u   // bf16 [9tap][8ocR][16kb][2h][32][8]
#define OFF_WFCP  6668800u   // bf16 packed fc_w
#define OFF_WOUTP 6701568u   // bf16 packed out_w
// end: 6767104 floats = 27.1 MB

typedef __attribute__((ext_vector_type(8))) short bf16x8;
typedef __attribute__((ext_vector_type(16))) float f32x16;

static __device__ __forceinline__ short f2b(float f) {
  __hip_bfloat16 h = __float2bfloat16(f);
  return *reinterpret_cast<short*>(&h);
}
static __device__ __forceinline__ float b2f(short s) {
  union { unsigned u; float f; } r;
  r.u = ((unsigned)(unsigned short)s) << 16;
  return r.f;
}

// expand 8 incidence bits (byte) -> bf16x8 of {0,1}  (pure VALU)
static __device__ __forceinline__ bf16x8 byte2bf(unsigned byte) {
  union { unsigned u[4]; bf16x8 h; } r;
  r.u[0] = ((byte * 0x8001u) & 0x10001u) * 0x3F80u;
  r.u[1] = (((byte >> 2) * 0x8001u) & 0x10001u) * 0x3F80u;
  r.u[2] = (((byte >> 4) * 0x8001u) & 0x10001u) * 0x3F80u;
  r.u[3] = (((byte >> 6) * 0x8001u) & 0x10001u) * 0x3F80u;
  return r.h;
}

// pack offset for element (row m, k c), K=256: [m>>5][c>>4][(c>>3)&1][m&31][c&7]
static __device__ __forceinline__ size_t packoff(int m, int c) {
  return ((size_t)((m >> 5) * 16 + (c >> 4)) * 2 + ((c >> 3) & 1)) * 256 + (m & 31) * 8 + (c & 7);
}

// ---------- fused front-end: transpose+pack+sq (blocks 0-255) | weight packers (256+) ----------
__global__ __launch_bounds__(256) void k_front2(const float* __restrict__ x,
                                                short* __restrict__ xp,
                                                float* __restrict__ sq,
                                                const float* __restrict__ fc_w,
                                                const float* __restrict__ ow,
                                                const float* __restrict__ dw,
                                                short* __restrict__ wfcp,
                                                short* __restrict__ woutp,
                                                short* __restrict__ w3p) {
  __shared__ float lds[256][33];
  __shared__ float red2[8][32];
  const int bid = blockIdx.x;
  const int t = threadIdx.x;
  if (bid < 256) {
    const int b = bid >> 7;
    const int n0 = (bid & 127) * 32;
    const float* xb = x + (size_t)b * CH * NPIX + n0;
    const int j = t & 31, cg8 = t >> 5;
#pragma unroll 4
    for (int it = 0; it < 32; ++it) {
      const int c = it * 8 + cg8;
      lds[c][j] = xb[(size_t)c * NPIX + j];
    }
    __syncthreads();
    {
      const int n = t & 31, cg = t >> 5;
      float s = 0.f;
#pragma unroll 8
      for (int i = 0; i < 32; ++i) {
        const float v = lds[cg * 32 + i][n];
        s += v * v;
      }
      red2[cg][n] = s;
    }
    short* xpb = xp + (size_t)b * NPIX * CH;
#pragma unroll
    for (int i = 0; i < 4; ++i) {
      const int f = i * 256 + t;
      const int n = f & 31, c0 = (f >> 5) * 8;
      short tmp[8];
#pragma unroll
      for (int k = 0; k < 8; ++k) tmp[k] = f2b(lds[c0 + k][n]);
      short* dst = xpb + packoff(n0 + n, c0);
      *(short4*)dst = *(short4*)&tmp[0];
      *(short4*)(dst + 4) = *(short4*)&tmp[4];
    }
    __syncthreads();
    if (t < 32) {
      float s = 0.f;
#pragma unroll
      for (int cg = 0; cg < 8; ++cg) s += red2[cg][t];
      sq[b * NPIX + n0 + t] = s;
    }
  } else {
    const int i = (bid - 256) * 256 + t;  // 786432
    if (i < 65536) {
      wfcp[packoff(i >> 8, i & 255)] = f2b(fc_w[i]);
    } else if (i < 196608) {
      const int j = i - 65536;
      woutp[packoff(j >> 8, j & 255)] = f2b(ow[j]);
    } else {
      const int j = i - 196608;        // dw[oc][c][kh][kw]
      const int oc = j / 2304;
      const int rem = j % 2304;
      const int c = rem / 9, tap = rem % 9;
      const size_t off = ((size_t)((tap * 8 + (oc >> 5)) * 16 + (c >> 4)) * 2 + ((c >> 3) & 1)) * 256
                       + (oc & 31) * 8 + (c & 7);
      w3p[off] = f2b(dw[j]);
    }
  }
}

// ---------- Gram: triangular 128x128 blocks (2 waves x 64x128), upper + mirrored writes ----------
__global__ __launch_bounds__(128, 2) void k_gram4(const short* __restrict__ xp,
                                                  const float* __restrict__ sq,
                                                  unsigned* __restrict__ hgbit) {
  const int b = blockIdx.z;
  int tt = blockIdx.x;
  int bi = (int)((65.0f - sqrtf(4225.0f - 8.0f * (float)tt)) * 0.5f);
  bi = bi < 0 ? 0 : (bi > 31 ? 31 : bi);
  while (bi * (65 - bi) / 2 > tt) --bi;
  while ((bi + 1) * (64 - bi) / 2 <= tt) ++bi;
  const int bj = bi + (tt - bi * (65 - bi) / 2);
  const int i0 = bi * 128, j0 = bj * 128;

  const int t = threadIdx.x;
  const int lane = t & 63, w = t >> 6;
  const int c = lane & 31, h = lane >> 5;
  const short* xb = xp + (size_t)b * NPIX * CH;
  const int ibase = i0 + w * 64;
  const int jbase = j0;

  f32x16 acc[2][4];
#pragma unroll
  for (int m = 0; m < 2; ++m)
#pragma unroll
    for (int n = 0; n < 4; ++n)
#pragma unroll
      for (int r = 0; r < 16; ++r) acc[m][n][r] = 0.f;

  const short* pa = xb + (size_t)(ibase >> 5) * 8192 + lane * 8;
  const short* pb = xb + (size_t)(jbase >> 5) * 8192 + lane * 8;

#pragma unroll 2
  for (int kb = 0; kb < 16; ++kb) {
    const bf16x8 a0 = *(const bf16x8*)(pa + kb * 512);
    const bf16x8 a1 = *(const bf16x8*)(pa + 8192 + kb * 512);
    bf16x8 bb[4];
#pragma unroll
    for (int n = 0; n < 4; ++n) bb[n] = *(const bf16x8*)(pb + (size_t)n * 8192 + kb * 512);
#pragma unroll
    for (int n = 0; n < 4; ++n) {
      acc[0][n] = __builtin_amdgcn_mfma_f32_32x32x16_bf16(a0, bb[n], acc[0][n], 0, 0, 0);
      acc[1][n] = __builtin_amdgcn_mfma_f32_32x32x16_bf16(a1, bb[n], acc[1][n], 0, 0, 0);
    }
  }

  const int sqb = b * NPIX;
#pragma unroll
  for (int m = 0; m < 2; ++m) {
    float4 sqa[4];
#pragma unroll
    for (int q = 0; q < 4; ++q)
      sqa[q] = *(const float4*)(sq + sqb + ibase + m * 32 + q * 8 + 4 * h);
#pragma unroll
    for (int n = 0; n < 4; ++n) {
      const float sj = sq[sqb + jbase + n * 32 + c];
      const int wj = (jbase + n * 32) >> 5;
      unsigned mmask = 0u;
#pragma unroll
      for (int q = 0; q < 4; ++q) {
        const float sqq[4] = {sqa[q].x, sqa[q].y, sqa[q].z, sqa[q].w};
#pragma unroll
        for (int rr = 0; rr < 4; ++rr) {
          const int reg = q * 4 + rr;
          const float d2 = sqq[rr] + sj - 2.f * acc[m][n][reg];
          const bool cond = d2 < 100.f;
          const unsigned long long bal = __ballot(cond);
          if ((lane & 31) == reg) {
            const int row = ibase + m * 32 + rr + 8 * q + 4 * h;
            const unsigned wd = h ? (unsigned)(bal >> 32) : (unsigned)bal;
            hgbit[(size_t)(sqb + row) * 128 + wj] = wd;
          }
          mmask |= (cond ? 1u : 0u) << (rr + 8 * q + 4 * h);
        }
      }
      // mirrored write: column (jbase+n*32+c) gets row-word for i-block
      const unsigned merged = mmask | (unsigned)__shfl_xor((int)mmask, 32, 64);
      if (h == 0) {
        const int colg = jbase + n * 32 + c;
        hgbit[(size_t)(sqb + colg) * 128 + ((ibase + m * 32) >> 5)] = merged;
      }
    }
  }
}

// ---------- fc GEMM (blocks 0-255) | 1/deg (blocks 256+) ----------
__global__ __launch_bounds__(256) void k_fcdinv(const short* __restrict__ wfcp,
                                                const short* __restrict__ xp,
                                                short* __restrict__ C,
                                                const float* __restrict__ bias,
                                                const unsigned* __restrict__ hg,
                                                float* __restrict__ dinvf) {
  const int bid = blockIdx.x;
  const int t = threadIdx.x;
  if (bid >= 256) {
    const int row = (bid - 256) * 4 + (t >> 6);
    const int l = t & 63;
    const unsigned w0 = hg[(size_t)row * 128 + l * 2];
    const unsigned w1 = hg[(size_t)row * 128 + l * 2 + 1];
    int n = __popc(w0) + __popc(w1);
#pragma unroll
    for (int off = 32; off; off >>= 1) n += __shfl_down(n, off);
    if (l == 0) dinvf[row] = 1.0f / (float)n;
    return;
  }
  const int b = bid >> 7;
  const short* xpb = xp + (size_t)b * NPIX * CH;
  short* Cb = C + ((size_t)b << 20);
  const int l = t & 63, wid = t >> 6;
  const int m0 = ((bid >> 6) & 1) * 128 + wid * 32, n0 = (bid & 63) * 64;
  const int col = l & 31, half = l >> 5;
  f32x16 acc[2];
#pragma unroll
  for (int nt = 0; nt < 2; ++nt)
#pragma unroll
    for (int r = 0; r < 16; ++r) acc[nt][r] = 0.f;
  const short* pa = wfcp + (size_t)(m0 >> 5) * 8192 + l * 8;
  const short* pb = xpb + (size_t)(n0 >> 5) * 8192 + l * 8;
#pragma unroll 4
  for (int kb = 0; kb < 16; ++kb) {
    const bf16x8 a = *(const bf16x8*)(pa + kb * 512);
    const bf16x8 b0 = *(const bf16x8*)(pb + kb * 512);
    const bf16x8 b1 = *(const bf16x8*)(pb + 8192 + kb * 512);
    acc[0] = __builtin_amdgcn_mfma_f32_32x32x16_bf16(a, b0, acc[0], 0, 0, 0);
    acc[1] = __builtin_amdgcn_mfma_f32_32x32x16_bf16(a, b1, acc[1], 0, 0, 0);
  }
  const int cb = m0 >> 5;
#pragma unroll
  for (int nt = 0; nt < 2; ++nt) {
    const int node = n0 + nt * 32 + col;
    short* dst = Cb + ((size_t)cb * 512 + (node >> 3)) * 256 + (node & 7);
#pragma unroll
    for (int q = 0; q < 4; ++q)
#pragma unroll
      for (int rr = 0; rr < 4; ++rr) {
        const int c31 = rr + 8 * q + 4 * half;
        dst[c31 * 8] = f2b(acc[nt][q * 4 + rr] + bias[m0 + c31]);
      }
  }
}

// ---------- hgemm_t4: E^T; 2 node tiles x 2 ch tiles per wave; 4 K-slices, LDS reduce ----------
__global__ __launch_bounds__(256) void k_hgemm_t4(const short* __restrict__ tbs,
                                                  const unsigned* __restrict__ hg,
                                                  const float* __restrict__ dinvf,
                                                  short* __restrict__ tbs2) {
  __shared__ float red[4][64][33];
  const int b = blockIdx.z;
  const int n0 = blockIdx.x * 64;
  const int cbp = blockIdx.y;
  const int ks = threadIdx.x >> 6;
  const int l = threadIdx.x & 63;
  const int col = l & 31, half = l >> 5;
  const int sh8 = half * 8;

  f32x16 acc00, acc01, acc10, acc11;
#pragma unroll
  for (int r = 0; r < 16; ++r) { acc00[r] = 0.f; acc01[r] = 0.f; acc10[r] = 0.f; acc11[r] = 0.f; }

  const short* pa0 = tbs + ((size_t)b << 20) + ((size_t)(cbp * 2) * 512 + half) * 256
                   + col * 8 + ks * 32768;
  const short* pa1 = pa0 + 131072;
  const uint4* hrow0 = (const uint4*)((const unsigned char*)hg
                     + ((size_t)b * NPIX + n0 + col) * 512 + ks * 128);
  const uint4* hrow1 = (const uint4*)((const unsigned char*)hg
                     + ((size_t)b * NPIX + n0 + 32 + col) * 512 + ks * 128);

#pragma unroll 2
  for (int o = 0; o < 8; ++o) {
    const uint4 wq0 = hrow0[o];
    const uint4 wq1 = hrow1[o];
    const unsigned ww0[4] = {wq0.x, wq0.y, wq0.z, wq0.w};
    const unsigned ww1[4] = {wq1.x, wq1.y, wq1.z, wq1.w};
#pragma unroll
    for (int s = 0; s < 4; ++s) {
      const bf16x8 a00 = *(const bf16x8*)(pa0);
      const bf16x8 a01 = *(const bf16x8*)(pa0 + 512);
      const bf16x8 a10 = *(const bf16x8*)(pa1);
      const bf16x8 a11 = *(const bf16x8*)(pa1 + 512);
      pa0 += 1024; pa1 += 1024;
      const bf16x8 b0 = byte2bf((ww0[s] >> sh8) & 0xFFu);
      const bf16x8 b1 = byte2bf((ww0[s] >> (16 + sh8)) & 0xFFu);
      const bf16x8 c0 = byte2bf((ww1[s] >> sh8) & 0xFFu);
      const bf16x8 c1 = byte2bf((ww1[s] >> (16 + sh8)) & 0xFFu);
      acc00 = __builtin_amdgcn_mfma_f32_32x32x16_bf16(a00, b0, acc00, 0, 0, 0);
      acc00 = __builtin_amdgcn_mfma_f32_32x32x16_bf16(a01, b1, acc00, 0, 0, 0);
      acc10 = __builtin_amdgcn_mfma_f32_32x32x16_bf16(a10, b0, acc10, 0, 0, 0);
      acc10 = __builtin_amdgcn_mfma_f32_32x32x16_bf16(a11, b1, acc10, 0, 0, 0);
      acc01 = __builtin_amdgcn_mfma_f32_32x32x16_bf16(a00, c0, acc01, 0, 0, 0);
      acc01 = __builtin_amdgcn_mfma_f32_32x32x16_bf16(a01, c1, acc01, 0, 0, 0);
      acc11 = __builtin_amdgcn_mfma_f32_32x32x16_bf16(a10, c0, acc11, 0, 0, 0);
      acc11 = __builtin_amdgcn_mfma_f32_32x32x16_bf16(a11, c1, acc11, 0, 0, 0);
    }
  }

#pragma unroll
  for (int r = 0; r < 16; ++r) { red[ks][l][r] = acc00[r]; red[ks][l][16 + r] = acc10[r]; }
  __syncthreads();
  {
    const int n = n0 + col;
    const float dinv = dinvf[b * NPIX + n];
    short* dst0 = tbs2 + ((size_t)b << 20) + ((size_t)(cbp * 2) * 512 + (n >> 3)) * 256 + (n & 7);
    short* dst1 = dst0 + 131072;
#pragma unroll
    for (int rj = 0; rj < 8; ++rj) {
      const int reg = ks * 8 + rj;
      const float s = red[0][l][reg] + red[1][l][reg] + red[2][l][reg] + red[3][l][reg];
      const int rm = reg & 15;
      const int c31 = (rm & 3) + 8 * (rm >> 2) + 4 * half;
      (reg < 16 ? dst0 : dst1)[c31 * 8] = f2b(s * dinv);
    }
  }
  __syncthreads();
#pragma unroll
  for (int r = 0; r < 16; ++r) { red[ks][l][r] = acc01[r]; red[ks][l][16 + r] = acc11[r]; }
  __syncthreads();
  {
    const int n = n0 + 32 + col;
    const float dinv = dinvf[b * NPIX + n];
    short* dst0 = tbs2 + ((size_t)b << 20) + ((size_t)(cbp * 2) * 512 + (n >> 3)) * 256 + (n & 7);
    short* dst1 = dst0 + 131072;
#pragma unroll
    for (int rj = 0; rj < 8; ++rj) {
      const int reg = ks * 8 + rj;
      const float s = red[0][l][reg] + red[1][l][reg] + red[2][l][reg] + red[3][l][reg];
      const int rm = reg & 15;
      const int c31 = (rm & 3) + 8 * (rm >> 2) + 4 * half;
      (reg < 16 ? dst0 : dst1)[c31 * 8] = f2b(s * dinv);
    }
  }
}

// ---------- hgemm_n4: v + fused BN partial stats ----------
__global__ __launch_bounds__(256) void k_hgemm_n4(const unsigned* __restrict__ hg,
                                                  const short* __restrict__ tbs2,
                                                  const float* __restrict__ dinvf,
                                                  const short* __restrict__ xp,
                                                  short* __restrict__ vb,
                                                  float* __restrict__ part) {
  __shared__ float red[4][64][33];
  __shared__ float bnp[128];
  const int b = blockIdx.z;
  const int cbp = blockIdx.x;
  const int m0 = blockIdx.y * 64;
  const int ks = threadIdx.x >> 6;
  const int l = threadIdx.x & 63;
  const int col = l & 31, half = l >> 5;
  const int sh8 = half * 8;
  if (threadIdx.x < 128) bnp[threadIdx.x] = 0.f;

  f32x16 acc00, acc01, acc10, acc11;
#pragma unroll
  for (int r = 0; r < 16; ++r) { acc00[r] = 0.f; acc01[r] = 0.f; acc10[r] = 0.f; acc11[r] = 0.f; }

  const short* pb0 = tbs2 + ((size_t)b << 20) + ((size_t)(cbp * 2) * 512 + half) * 256
                   + col * 8 + ks * 32768;
  const short* pb1 = pb0 + 131072;
  const uint4* hrow0 = (const uint4*)((const unsigned char*)hg
                     + ((size_t)b * NPIX + m0 + col) * 512 + ks * 128);
  const uint4* hrow1 = (const uint4*)((const unsigned char*)hg
                     + ((size_t)b * NPIX + m0 + 32 + col) * 512 + ks * 128);

#pragma unroll 2
  for (int o = 0; o < 8; ++o) {
    const uint4 wq0 = hrow0[o];
    const uint4 wq1 = hrow1[o];
    const unsigned ww0[4] = {wq0.x, wq0.y, wq0.z, wq0.w};
    const unsigned ww1[4] = {wq1.x, wq1.y, wq1.z, wq1.w};
#pragma unroll
    for (int s = 0; s < 4; ++s) {
      const bf16x8 b00 = *(const bf16x8*)(pb0);
      const bf16x8 b01 = *(const bf16x8*)(pb0 + 512);
      const bf16x8 b10 = *(const bf16x8*)(pb1);
      const bf16x8 b11 = *(const bf16x8*)(pb1 + 512);
      pb0 += 1024; pb1 += 1024;
      const bf16x8 a0 = byte2bf((ww0[s] >> sh8) & 0xFFu);
      const bf16x8 a1 = byte2bf((ww0[s] >> (16 + sh8)) & 0xFFu);
      const bf16x8 a2 = byte2bf((ww1[s] >> sh8) & 0xFFu);
      const bf16x8 a3 = byte2bf((ww1[s] >> (16 + sh8)) & 0xFFu);
      acc00 = __builtin_amdgcn_mfma_f32_32x32x16_bf16(a0, b00, acc00, 0, 0, 0);
      acc00 = __builtin_amdgcn_mfma_f32_32x32x16_bf16(a1, b01, acc00, 0, 0, 0);
      acc01 = __builtin_amdgcn_mfma_f32_32x32x16_bf16(a0, b10, acc01, 0, 0, 0);
      acc01 = __builtin_amdgcn_mfma_f32_32x32x16_bf16(a1, b11, acc01, 0, 0, 0);
      acc10 = __builtin_amdgcn_mfma_f32_32x32x16_bf16(a2, b00, acc10, 0, 0, 0);
      acc10 = __builtin_amdgcn_mfma_f32_32x32x16_bf16(a3, b01, acc10, 0, 0, 0);
      acc11 = __builtin_amdgcn_mfma_f32_32x32x16_bf16(a2, b10, acc11, 0, 0, 0);
      acc11 = __builtin_amdgcn_mfma_f32_32x32x16_bf16(a3, b11, acc11, 0, 0, 0);
    }
  }

  const short* xpb = xp + (size_t)b * NPIX * CH;
  // round A: node tile 0
#pragma unroll
  for (int r = 0; r < 16; ++r) { red[ks][l][r] = acc00[r]; red[ks][l][16 + r] = acc01[r]; }
  __syncthreads();
  {
    const int cc = cbp * 64 + col;
#pragma unroll
    for (int rj = 0; rj < 8; ++rj) {
      const int reg = ks * 8 + rj;
      const float s = red[0][l][reg] + red[1][l][reg] + red[2][l][reg] + red[3][l][reg];
      const int rm = reg & 15;
      const int r = m0 + (rm & 3) + 8 * (rm >> 2) + 4 * half;
      const int ccc = cc + (reg < 16 ? 0 : 32);
      const size_t o = ((size_t)(b * NPIX + r)) * CH + ccc;
      const short sv = f2b(s * dinvf[b * NPIX + r] + b2f(xpb[packoff(r, ccc)]));
      vb[o] = sv;
      const float vr = b2f(sv);
      const int ci = col + (reg < 16 ? 0 : 32);
      atomicAdd(&bnp[ci], vr);
      atomicAdd(&bnp[64 + ci], vr * vr);
    }
  }
  __syncthreads();
  // round B: node tile 1
#pragma unroll
  for (int r = 0; r < 16; ++r) { red[ks][l][r] = acc10[r]; red[ks][l][16 + r] = acc11[r]; }
  __syncthreads();
  {
    const int cc = cbp * 64 + col;
#pragma unroll
    for (int rj = 0; rj < 8; ++rj) {
      const int reg = ks * 8 + rj;
      const float s = red[0][l][reg] + red[1][l][reg] + red[2][l][reg] + red[3][l][reg];
      const int rm = reg & 15;
      const int r = m0 + 32 + (rm & 3) + 8 * (rm >> 2) + 4 * half;
      const int ccc = cc + (reg < 16 ? 0 : 32);
      const size_t o = ((size_t)(b * NPIX + r)) * CH + ccc;
      const short sv = f2b(s * dinvf[b * NPIX + r] + b2f(xpb[packoff(r, ccc)]));
      vb[o] = sv;
      const float vr = b2f(sv);
      const int ci = col + (reg < 16 ? 0 : 32);
      atomicAdd(&bnp[ci], vr);
      atomicAdd(&bnp[64 + ci], vr * vr);
    }
  }
  __syncthreads();
  if (threadIdx.x < 128) {
    const int slot = b * 64 + blockIdx.y;
    part[((size_t)(cbp * 128 + slot)) * 128 + threadIdx.x] = bnp[threadIdx.x];
  }
}

// ---------- BN finalize (reads fused partials) ----------
__global__ void k_bnfin(const float* __restrict__ part, const float* __restrict__ gamma,
                        const float* __restrict__ beta, float* __restrict__ bnss) {
  const int t = threadIdx.x;  // 256: channel
  const int cbp = t >> 6, ch = t & 63;
  float s = 0.f, ss = 0.f;
  for (int i = 0; i < 128; ++i) {
    const float* p = part + ((size_t)(cbp * 128 + i)) * 128;
    s += p[ch];
    ss += p[64 + ch];
  }
  const float mean = s * (1.f / 8192.f);
  const float var = ss * (1.f / 8192.f) - mean * mean;
  const float inv = rsqrtf(var + 1e-5f);
  const float sc = gamma[t] * inv;
  bnss[t] = sc;
  bnss[256 + t] = beta[t] - mean * sc;
}

// ---------- BN apply + SiLU (bf16 in) -> conv input pack ----------
__global__ void k_bnapply3(const short* __restrict__ vb, const float* __restrict__ bnss,
                           short* __restrict__ xpp) {
  const int i = blockIdx.x * 256 + threadIdx.x;  // 524288 short4 groups
  const short4 sv = reinterpret_cast<const short4*>(vb)[i];
  const int c0 = (i & 63) * 4;
  const int n = (i >> 6) & 4095;
  const int b = i >> 18;
  const float4 sc = *(const float4*)(bnss + c0);
  const float4 sh = *(const float4*)(bnss + 256 + c0);
  const float u0 = b2f(sv.x) * sc.x + sh.x;
  const float u1 = b2f(sv.y) * sc.y + sh.y;
  const float u2 = b2f(sv.z) * sc.z + sh.z;
  const float u3 = b2f(sv.w) * sc.w + sh.w;
  short4 o;
  o.x = f2b(u0 / (1.f + expf(-u0)));
  o.y = f2b(u1 / (1.f + expf(-u1)));
  o.z = f2b(u2 / (1.f + expf(-u2)));
  o.w = f2b(u3 / (1.f + expf(-u3)));
  const int ih = n >> 6, iw = n & 63;
  const int p = iw & 1, ow = iw >> 1;
  const size_t off = ((size_t)(((b * 2 + p) * 64 + ih) * 16 + (c0 >> 4)) * 2 + ((c0 >> 3) & 1)) * 256
                   + ow * 8 + (c0 & 7);
  *(short4*)(xpp + off) = o;
}

// ---------- 3x3 stride-2 conv via packed MFMA, channel-split 4-way ----------
__global__ __launch_bounds__(64) void k_conv5(const short* __restrict__ xpp,
                                              const short* __restrict__ w3p,
                                              float* __restrict__ convp) {
  const int ocg = blockIdx.x;
  const int oh = blockIdx.y;
  const int bz = blockIdx.z;    // cs*2 + b (8)
  const int b = bz & 1, cs = bz >> 1;
  const int l = threadIdx.x;
  const int col = l & 31;
  const bf16x8 zv = {0, 0, 0, 0, 0, 0, 0, 0};

  f32x16 acc;
#pragma unroll
  for (int r = 0; r < 16; ++r) acc[r] = 0.f;

  for (int kh = 0; kh < 3; ++kh) {
    const int ih = 2 * oh + kh;
    if (ih >= 64) continue;
#pragma unroll
    for (int kw = 0; kw < 3; ++kw) {
      const int p = kw & 1;
      const short* pa = xpp + ((size_t)((b * 2 + p) * 64 + ih) * 16 + cs * 4) * 512
                      + l * 8 + (kw == 2 ? 8 : 0);
      const short* pb = w3p + ((size_t)((kh * 3 + kw) * 8 + ocg) * 16 + cs * 4) * 512 + l * 8;
      const bool kill = (kw == 2) && (col == 31);
#pragma unroll
      for (int kb = 0; kb < 4; ++kb) {
        bf16x8 a = *(const bf16x8*)(pa + kb * 512);
        if (kill) a = zv;
        const bf16x8 bb = *(const bf16x8*)(pb + kb * 512);
        acc = __builtin_amdgcn_mfma_f32_32x32x16_bf16(a, bb, acc, 0, 0, 0);
      }
    }
  }
  const int half = l >> 5;
  const int oc = ocg * 32 + col;
#pragma unroll
  for (int q = 0; q < 4; ++q)
#pragma unroll
    for (int rr = 0; rr < 4; ++rr) {
      const int ow = rr + 8 * q + 4 * half;
      convp[((size_t)bz * 1024 + oh * 32 + ow) * 256 + oc] = acc[q * 4 + rr];
    }
}

// ---------- merge conv quarters + bias -> packed bf16 xdtb ----------
__global__ void k_convmerge3(const float* __restrict__ convp, const float* __restrict__ db,
                             short* __restrict__ xdtb) {
  const int i = blockIdx.x * 256 + threadIdx.x;  // 131072 groups of 4
  const int b = i >> 16, px = (i >> 6) & 1023, oc0 = (i & 63) * 4;
  const size_t base = ((size_t)px) * 256 + oc0;
  const float4 h0 = *(const float4*)(convp + ((size_t)(0 + b) << 18) + base);
  const float4 h1 = *(const float4*)(convp + ((size_t)(2 + b) << 18) + base);
  const float4 h2 = *(const float4*)(convp + ((size_t)(4 + b) << 18) + base);
  const float4 h3 = *(const float4*)(convp + ((size_t)(6 + b) << 18) + base);
  const float4 bv = *(const float4*)(db + oc0);
  short4 o;
  o.x = f2b(h0.x + h1.x + h2.x + h3.x + bv.x);
  o.y = f2b(h0.y + h1.y + h2.y + h3.y + bv.y);
  o.z = f2b(h0.z + h1.z + h2.z + h3.z + bv.z);
  o.w = f2b(h0.w + h1.w + h2.w + h3.w + bv.w);
  const size_t off = ((size_t)((b * 32 + (px >> 5)) * 16 + (oc0 >> 4)) * 2 + ((oc0 >> 3) & 1)) * 256
                   + (px & 31) * 8 + (oc0 & 7);
  *(short4*)(xdtb + off) = o;
}

// ---------- final 1x1 GEMM on packed operands, f32 out + row bias ----------
__global__ __launch_bounds__(256) void k_mfma_nt2(const short* __restrict__ woutp,
                                                  const short* __restrict__ xdtb,
                                                  float* __restrict__ C,
                                                  const float* __restrict__ bias) {
  const int b = blockIdx.z;
  xdtb += (size_t)b * 1024 * CH;
  C += (size_t)b * 512 * 1024;
  const int t = threadIdx.x, l = t & 63, wid = t >> 6;
  const int m0 = blockIdx.y * 128 + wid * 32, n0 = blockIdx.x * 64;
  const int col = l & 31, half = l >> 5;
  f32x16 acc[2];
#pragma unroll
  for (int nt = 0; nt < 2; ++nt)
#pragma unroll
    for (int r = 0; r < 16; ++r) acc[nt][r] = 0.f;
  const short* pa = woutp + (size_t)(m0 >> 5) * 8192 + l * 8;
  const short* pb = xdtb + (size_t)(n0 >> 5) * 8192 + l * 8;
#pragma unroll 4
  for (int kb = 0; kb < 16; ++kb) {
    const bf16x8 a = *(const bf16x8*)(pa + kb * 512);
    const bf16x8 b0 = *(const bf16x8*)(pb + kb * 512);
    const bf16x8 b1 = *(const bf16x8*)(pb + 8192 + kb * 512);
    acc[0] = __builtin_amdgcn_mfma_f32_32x32x16_bf16(a, b0, acc[0], 0, 0, 0);
    acc[1] = __builtin_amdgcn_mfma_f32_32x32x16_bf16(a, b1, acc[1], 0, 0, 0);
  }
#pragma unroll
  for (int nt = 0; nt < 2; ++nt) {
#pragma unroll
    for (int q = 0; q < 4; ++q)
#pragma unroll
      for (int rr = 0; rr < 4; ++rr) {
        const int row = m0 + rr + 8 * q + 4 * half;
        const int cc = n0 + nt * 32 + col;
        C[(size_t)row * 1024 + cc] = acc[nt][q * 4 + rr] + bias[row];
      }
  }
}

extern "C" void kernel_launch(void* const* d_in, const int* in_sizes, int n_in,
                              void* d_out, int out_size, void* d_ws, size_t ws_size,
                              hipStream_t stream) {
  const float* x     = (const float*)d_in[0];
  const float* fc_w  = (const float*)d_in[1];
  const float* fc_b  = (const float*)d_in[2];
  const float* gamma = (const float*)d_in[3];
  const float* beta  = (const float*)d_in[4];
  const float* dw    = (const float*)d_in[5];
  const float* db    = (const float*)d_in[6];
  const float* ow    = (const float*)d_in[7];
  const float* ob    = (const float*)d_in[8];

  float* ws   = (float*)d_ws;
  short* xp   = (short*)(ws + OFF_XP);
  float* convp= ws + OFF_XP;              // 8 MB: XP+XR (both dead after hgemm_n4)
  short* vb   = (short*)(ws + OFF_VB);
  short* tbs  = (short*)(ws + OFF_TBS);   // y^T; later xdtb
  short* xdtb = (short*)(ws + OFF_TBS);
  short* tbs2 = (short*)(ws + OFF_TBS2);  // E^T; later xpp
  short* xpp  = (short*)(ws + OFF_TBS2);
  unsigned* hg = (unsigned*)(ws + OFF_HG);
  float* sqv  = ws + OFF_SQ;
  float* part = ws + OFF_PART;
  float* bnss = ws + OFF_BNSS;
  float* dinvf= ws + OFF_DINV;
  short* w3p  = (short*)(ws + OFF_W3P);
  short* wfcp = (short*)(ws + OFF_WFCP);
  short* woutp= (short*)(ws + OFF_WOUTP);
  float* out  = (float*)d_out;

  // fused: transpose+pack+sq (256 blocks) | weight packs (3072 blocks)
  k_front2<<<3328, 256, 0, stream>>>(x, xp, sqv, fc_w, ow, dw, wfcp, woutp, w3p);
  // Gram: triangular 128x128 blocks (2 waves), writes upper + mirrored words directly
  k_gram4<<<dim3(528, 1, 2), 128, 0, stream>>>(xp, sqv, hg);
  // fused: fc GEMM (256 blocks) | 1/deg (2048 blocks)
  k_fcdinv<<<2304, 256, 0, stream>>>(wfcp, xp, tbs, fc_b, hg, dinvf);
  // E^T: 2 node tiles/wave share value loads; 4 K-slices, LDS reduce + dinv
  k_hgemm_t4<<<dim3(64, 4, 2), 256, 0, stream>>>(tbs, hg, dinvf, tbs2);
  // v: same structure + fused BN partial stats
  k_hgemm_n4<<<dim3(4, 64, 2), 256, 0, stream>>>(hg, tbs2, dinvf, xp, vb, part);
  k_bnfin<<<1, 256, 0, stream>>>(part, gamma, beta, bnss);
  k_bnapply3<<<2048, 256, 0, stream>>>(vb, bnss, xpp);
  // 3x3 s2 conv (packed MFMA, K split 4-way) -> f32 partials -> packed bf16
  k_conv5<<<dim3(8, 32, 8), 64, 0, stream>>>(xpp, w3p, convp);
  k_convmerge3<<<512, 256, 0, stream>>>(convp, db, xdtb);
  // out = out_w @ xdT^T + out_b
  k_mfma_nt2<<<dim3(16, 4, 2), 256, 0, stream>>>(woutp, xdtb, out, ob);
}

// Round 17
// 132.586 us; speedup vs baseline: 1.0591x; 1.0591x over previous
//
#include <hip/hip_runtime.h>
#include <hip/hip_bf16.h>
#include <math.h>

#define NPIX 4096
#define CH   256

// ---- ws float offsets ----
#define OFF_XP    0u         // bf16 packed x; later convp f32 [8][1024][256] (spans XP+XR)
#define OFF_XR    1048576u   // (free; convp upper half)
#define OFF_VB    2097152u   // bf16 v [2][4096][256] (BN input)
#define OFF_TBS   3145728u   // bf16 swizzled y^T; later xdtb pack
#define OFF_TBS2  4194304u   // bf16 swizzled E^T; later xpp conv input pack
#define OFF_HG    5242880u   // uint32 [2][4096][128] incidence bitmask
#define OFF_SQ    6291456u   // [8192] f32
#define OFF_PART  6299648u   // [128][512] f32 BN partials
#define OFF_BNSS  6365184u   // [512] f32
#define OFF_DINV  6365696u   // [8192] f32 1/deg
#define OFF_W3P   6373888u   // bf16 [9tap][8ocR][16kb][2h][32][8]
#define OFF_WFCP  6668800u   // bf16 packed fc_w
#define OFF_WOUTP 6701568u   // bf16 packed out_w
// end: 6767104 floats = 27.1 MB

typedef __attribute__((ext_vector_type(8))) short bf16x8;
typedef __attribute__((ext_vector_type(16))) float f32x16;

static __device__ __forceinline__ short f2b(float f) {
  __hip_bfloat16 h = __float2bfloat16(f);
  return *reinterpret_cast<short*>(&h);
}
static __device__ __forceinline__ float b2f(short s) {
  union { unsigned u; float f; } r;
  r.u = ((unsigned)(unsigned short)s) << 16;
  return r.f;
}

// expand 8 incidence bits (byte) -> bf16x8 of {0,1}  (pure VALU)
static __device__ __forceinline__ bf16x8 byte2bf(unsigned byte) {
  union { unsigned u[4]; bf16x8 h; } r;
  r.u[0] = ((byte * 0x8001u) & 0x10001u) * 0x3F80u;
  r.u[1] = (((byte >> 2) * 0x8001u) & 0x10001u) * 0x3F80u;
  r.u[2] = (((byte >> 4) * 0x8001u) & 0x10001u) * 0x3F80u;
  r.u[3] = (((byte >> 6) * 0x8001u) & 0x10001u) * 0x3F80u;
  return r.h;
}

// pack offset for element (row m, k c), K=256: [m>>5][c>>4][(c>>3)&1][m&31][c&7]
static __device__ __forceinline__ size_t packoff(int m, int c) {
  return ((size_t)((m >> 5) * 16 + (c >> 4)) * 2 + ((c >> 3) & 1)) * 256 + (m & 31) * 8 + (c & 7);
}

// ---------- fused front-end: transpose+pack+sq (blocks 0-255) | weight packers (256+) ----------
__global__ __launch_bounds__(256) void k_front2(const float* __restrict__ x,
                                                short* __restrict__ xp,
                                                float* __restrict__ sq,
                                                const float* __restrict__ fc_w,
                                                const float* __restrict__ ow,
                                                const float* __restrict__ dw,
                                                short* __restrict__ wfcp,
                                                short* __restrict__ woutp,
                                                short* __restrict__ w3p) {
  __shared__ float lds[256][33];
  __shared__ float red2[8][32];
  const int bid = blockIdx.x;
  const int t = threadIdx.x;
  if (bid < 256) {
    const int b = bid >> 7;
    const int n0 = (bid & 127) * 32;
    const float* xb = x + (size_t)b * CH * NPIX + n0;
    const int j = t & 31, cg8 = t >> 5;
#pragma unroll 4
    for (int it = 0; it < 32; ++it) {
      const int c = it * 8 + cg8;
      lds[c][j] = xb[(size_t)c * NPIX + j];
    }
    __syncthreads();
    {
      const int n = t & 31, cg = t >> 5;
      float s = 0.f;
#pragma unroll 8
      for (int i = 0; i < 32; ++i) {
        const float v = lds[cg * 32 + i][n];
        s += v * v;
      }
      red2[cg][n] = s;
    }
    short* xpb = xp + (size_t)b * NPIX * CH;
#pragma unroll
    for (int i = 0; i < 4; ++i) {
      const int f = i * 256 + t;
      const int n = f & 31, c0 = (f >> 5) * 8;
      short tmp[8];
#pragma unroll
      for (int k = 0; k < 8; ++k) tmp[k] = f2b(lds[c0 + k][n]);
      short* dst = xpb + packoff(n0 + n, c0);
      *(short4*)dst = *(short4*)&tmp[0];
      *(short4*)(dst + 4) = *(short4*)&tmp[4];
    }
    __syncthreads();
    if (t < 32) {
      float s = 0.f;
#pragma unroll
      for (int cg = 0; cg < 8; ++cg) s += red2[cg][t];
      sq[b * NPIX + n0 + t] = s;
    }
  } else {
    const int i = (bid - 256) * 256 + t;  // 786432
    if (i < 65536) {
      wfcp[packoff(i >> 8, i & 255)] = f2b(fc_w[i]);
    } else if (i < 196608) {
      const int j = i - 65536;
      woutp[packoff(j >> 8, j & 255)] = f2b(ow[j]);
    } else {
      const int j = i - 196608;        // dw[oc][c][kh][kw]
      const int oc = j / 2304;
      const int rem = j % 2304;
      const int c = rem / 9, tap = rem % 9;
      const size_t off = ((size_t)((tap * 8 + (oc >> 5)) * 16 + (c >> 4)) * 2 + ((c >> 3) & 1)) * 256
                       + (oc & 31) * 8 + (c & 7);
      w3p[off] = f2b(dw[j]);
    }
  }
}

// ---------- Gram: triangular 128x128 blocks (2 waves x 64x128), upper + mirrored writes ----------
__global__ __launch_bounds__(128, 2) void k_gram4(const short* __restrict__ xp,
                                                  const float* __restrict__ sq,
                                                  unsigned* __restrict__ hgbit) {
  const int b = blockIdx.z;
  int tt = blockIdx.x;
  int bi = (int)((65.0f - sqrtf(4225.0f - 8.0f * (float)tt)) * 0.5f);
  bi = bi < 0 ? 0 : (bi > 31 ? 31 : bi);
  while (bi * (65 - bi) / 2 > tt) --bi;
  while ((bi + 1) * (64 - bi) / 2 <= tt) ++bi;
  const int bj = bi + (tt - bi * (65 - bi) / 2);
  const int i0 = bi * 128, j0 = bj * 128;

  const int t = threadIdx.x;
  const int lane = t & 63, w = t >> 6;
  const int c = lane & 31, h = lane >> 5;
  const short* xb = xp + (size_t)b * NPIX * CH;
  const int ibase = i0 + w * 64;
  const int jbase = j0;

  f32x16 acc[2][4];
#pragma unroll
  for (int m = 0; m < 2; ++m)
#pragma unroll
    for (int n = 0; n < 4; ++n)
#pragma unroll
      for (int r = 0; r < 16; ++r) acc[m][n][r] = 0.f;

  const short* pa = xb + (size_t)(ibase >> 5) * 8192 + lane * 8;
  const short* pb = xb + (size_t)(jbase >> 5) * 8192 + lane * 8;

#pragma unroll 2
  for (int kb = 0; kb < 16; ++kb) {
    const bf16x8 a0 = *(const bf16x8*)(pa + kb * 512);
    const bf16x8 a1 = *(const bf16x8*)(pa + 8192 + kb * 512);
    bf16x8 bb[4];
#pragma unroll
    for (int n = 0; n < 4; ++n) bb[n] = *(const bf16x8*)(pb + (size_t)n * 8192 + kb * 512);
#pragma unroll
    for (int n = 0; n < 4; ++n) {
      acc[0][n] = __builtin_amdgcn_mfma_f32_32x32x16_bf16(a0, bb[n], acc[0][n], 0, 0, 0);
      acc[1][n] = __builtin_amdgcn_mfma_f32_32x32x16_bf16(a1, bb[n], acc[1][n], 0, 0, 0);
    }
  }

  const int sqb = b * NPIX;
#pragma unroll
  for (int m = 0; m < 2; ++m) {
    float4 sqa[4];
#pragma unroll
    for (int q = 0; q < 4; ++q)
      sqa[q] = *(const float4*)(sq + sqb + ibase + m * 32 + q * 8 + 4 * h);
#pragma unroll
    for (int n = 0; n < 4; ++n) {
      const float sj = sq[sqb + jbase + n * 32 + c];
      const int wj = (jbase + n * 32) >> 5;
      unsigned mmask = 0u;
#pragma unroll
      for (int q = 0; q < 4; ++q) {
        const float sqq[4] = {sqa[q].x, sqa[q].y, sqa[q].z, sqa[q].w};
#pragma unroll
        for (int rr = 0; rr < 4; ++rr) {
          const int reg = q * 4 + rr;
          const float d2 = sqq[rr] + sj - 2.f * acc[m][n][reg];
          const bool cond = d2 < 100.f;
          const unsigned long long bal = __ballot(cond);
          if ((lane & 31) == reg) {
            const int row = ibase + m * 32 + rr + 8 * q + 4 * h;
            const unsigned wd = h ? (unsigned)(bal >> 32) : (unsigned)bal;
            hgbit[(size_t)(sqb + row) * 128 + wj] = wd;
          }
          mmask |= (cond ? 1u : 0u) << (rr + 8 * q + 4 * h);
        }
      }
      const unsigned merged = mmask | (unsigned)__shfl_xor((int)mmask, 32, 64);
      if (h == 0) {
        const int colg = jbase + n * 32 + c;
        hgbit[(size_t)(sqb + colg) * 128 + ((ibase + m * 32) >> 5)] = merged;
      }
    }
  }
}

// ---------- fc GEMM (blocks 0-255) | 1/deg (blocks 256+) ----------
__global__ __launch_bounds__(256) void k_fcdinv(const short* __restrict__ wfcp,
                                                const short* __restrict__ xp,
                                                short* __restrict__ C,
                                                const float* __restrict__ bias,
                                                const unsigned* __restrict__ hg,
                                                float* __restrict__ dinvf) {
  const int bid = blockIdx.x;
  const int t = threadIdx.x;
  if (bid >= 256) {
    const int row = (bid - 256) * 4 + (t >> 6);
    const int l = t & 63;
    const unsigned w0 = hg[(size_t)row * 128 + l * 2];
    const unsigned w1 = hg[(size_t)row * 128 + l * 2 + 1];
    int n = __popc(w0) + __popc(w1);
#pragma unroll
    for (int off = 32; off; off >>= 1) n += __shfl_down(n, off);
    if (l == 0) dinvf[row] = 1.0f / (float)n;
    return;
  }
  const int b = bid >> 7;
  const short* xpb = xp + (size_t)b * NPIX * CH;
  short* Cb = C + ((size_t)b << 20);
  const int l = t & 63, wid = t >> 6;
  const int m0 = ((bid >> 6) & 1) * 128 + wid * 32, n0 = (bid & 63) * 64;
  const int col = l & 31, half = l >> 5;
  f32x16 acc[2];
#pragma unroll
  for (int nt = 0; nt < 2; ++nt)
#pragma unroll
    for (int r = 0; r < 16; ++r) acc[nt][r] = 0.f;
  const short* pa = wfcp + (size_t)(m0 >> 5) * 8192 + l * 8;
  const short* pb = xpb + (size_t)(n0 >> 5) * 8192 + l * 8;
#pragma unroll 4
  for (int kb = 0; kb < 16; ++kb) {
    const bf16x8 a = *(const bf16x8*)(pa + kb * 512);
    const bf16x8 b0 = *(const bf16x8*)(pb + kb * 512);
    const bf16x8 b1 = *(const bf16x8*)(pb + 8192 + kb * 512);
    acc[0] = __builtin_amdgcn_mfma_f32_32x32x16_bf16(a, b0, acc[0], 0, 0, 0);
    acc[1] = __builtin_amdgcn_mfma_f32_32x32x16_bf16(a, b1, acc[1], 0, 0, 0);
  }
  const int cb = m0 >> 5;
#pragma unroll
  for (int nt = 0; nt < 2; ++nt) {
    const int node = n0 + nt * 32 + col;
    short* dst = Cb + ((size_t)cb * 512 + (node >> 3)) * 256 + (node & 7);
#pragma unroll
    for (int q = 0; q < 4; ++q)
#pragma unroll
      for (int rr = 0; rr < 4; ++rr) {
        const int c31 = rr + 8 * q + 4 * half;
        dst[c31 * 8] = f2b(acc[nt][q * 4 + rr] + bias[m0 + c31]);
      }
  }
}

// ---------- hgemm_t5: E^T; 2 node x 2 ch tiles/wave; 8 waves = 8 K-slices, LDS reduce ----------
__global__ __launch_bounds__(512) void k_hgemm_t5(const short* __restrict__ tbs,
                                                  const unsigned* __restrict__ hg,
                                                  const float* __restrict__ dinvf,
                                                  short* __restrict__ tbs2) {
  __shared__ float red[8][64][33];
  const int b = blockIdx.z;
  const int n0 = blockIdx.x * 64;
  const int cbp = blockIdx.y;
  const int ks = threadIdx.x >> 6;   // 8 K-slices of 512
  const int l = threadIdx.x & 63;
  const int col = l & 31, half = l >> 5;
  const int sh8 = half * 8;

  f32x16 acc00, acc01, acc10, acc11;
#pragma unroll
  for (int r = 0; r < 16; ++r) { acc00[r] = 0.f; acc01[r] = 0.f; acc10[r] = 0.f; acc11[r] = 0.f; }

  const short* pa0 = tbs + ((size_t)b << 20) + ((size_t)(cbp * 2) * 512 + half) * 256
                   + col * 8 + ks * 16384;
  const short* pa1 = pa0 + 131072;
  const uint4* hrow0 = (const uint4*)((const unsigned char*)hg
                     + ((size_t)b * NPIX + n0 + col) * 512 + ks * 64);
  const uint4* hrow1 = (const uint4*)((const unsigned char*)hg
                     + ((size_t)b * NPIX + n0 + 32 + col) * 512 + ks * 64);

#pragma unroll
  for (int o = 0; o < 4; ++o) {
    const uint4 wq0 = hrow0[o];
    const uint4 wq1 = hrow1[o];
    const unsigned ww0[4] = {wq0.x, wq0.y, wq0.z, wq0.w};
    const unsigned ww1[4] = {wq1.x, wq1.y, wq1.z, wq1.w};
#pragma unroll
    for (int s = 0; s < 4; ++s) {
      const bf16x8 a00 = *(const bf16x8*)(pa0);
      const bf16x8 a01 = *(const bf16x8*)(pa0 + 512);
      const bf16x8 a10 = *(const bf16x8*)(pa1);
      const bf16x8 a11 = *(const bf16x8*)(pa1 + 512);
      pa0 += 1024; pa1 += 1024;
      const bf16x8 b0 = byte2bf((ww0[s] >> sh8) & 0xFFu);
      const bf16x8 b1 = byte2bf((ww0[s] >> (16 + sh8)) & 0xFFu);
      const bf16x8 c0 = byte2bf((ww1[s] >> sh8) & 0xFFu);
      const bf16x8 c1 = byte2bf((ww1[s] >> (16 + sh8)) & 0xFFu);
      acc00 = __builtin_amdgcn_mfma_f32_32x32x16_bf16(a00, b0, acc00, 0, 0, 0);
      acc00 = __builtin_amdgcn_mfma_f32_32x32x16_bf16(a01, b1, acc00, 0, 0, 0);
      acc10 = __builtin_amdgcn_mfma_f32_32x32x16_bf16(a10, b0, acc10, 0, 0, 0);
      acc10 = __builtin_amdgcn_mfma_f32_32x32x16_bf16(a11, b1, acc10, 0, 0, 0);
      acc01 = __builtin_amdgcn_mfma_f32_32x32x16_bf16(a00, c0, acc01, 0, 0, 0);
      acc01 = __builtin_amdgcn_mfma_f32_32x32x16_bf16(a01, c1, acc01, 0, 0, 0);
      acc11 = __builtin_amdgcn_mfma_f32_32x32x16_bf16(a10, c0, acc11, 0, 0, 0);
      acc11 = __builtin_amdgcn_mfma_f32_32x32x16_bf16(a11, c1, acc11, 0, 0, 0);
    }
  }

  // round A: node tile 0 (acc00=cb0, acc10=cb1)
#pragma unroll
  for (int r = 0; r < 16; ++r) { red[ks][l][r] = acc00[r]; red[ks][l][16 + r] = acc10[r]; }
  __syncthreads();
  {
    const int n = n0 + col;
    const float dinv = dinvf[b * NPIX + n];
    short* dst0 = tbs2 + ((size_t)b << 20) + ((size_t)(cbp * 2) * 512 + (n >> 3)) * 256 + (n & 7);
    short* dst1 = dst0 + 131072;
#pragma unroll
    for (int rj = 0; rj < 4; ++rj) {
      const int reg = ks * 4 + rj;
      float s = 0.f;
#pragma unroll
      for (int w = 0; w < 8; ++w) s += red[w][l][reg];
      const int rm = reg & 15;
      const int c31 = (rm & 3) + 8 * (rm >> 2) + 4 * half;
      (reg < 16 ? dst0 : dst1)[c31 * 8] = f2b(s * dinv);
    }
  }
  __syncthreads();
  // round B: node tile 1 (acc01=cb0, acc11=cb1)
#pragma unroll
  for (int r = 0; r < 16; ++r) { red[ks][l][r] = acc01[r]; red[ks][l][16 + r] = acc11[r]; }
  __syncthreads();
  {
    const int n = n0 + 32 + col;
    const float dinv = dinvf[b * NPIX + n];
    short* dst0 = tbs2 + ((size_t)b << 20) + ((size_t)(cbp * 2) * 512 + (n >> 3)) * 256 + (n & 7);
    short* dst1 = dst0 + 131072;
#pragma unroll
    for (int rj = 0; rj < 4; ++rj) {
      const int reg = ks * 4 + rj;
      float s = 0.f;
#pragma unroll
      for (int w = 0; w < 8; ++w) s += red[w][l][reg];
      const int rm = reg & 15;
      const int c31 = (rm & 3) + 8 * (rm >> 2) + 4 * half;
      (reg < 16 ? dst0 : dst1)[c31 * 8] = f2b(s * dinv);
    }
  }
}

// ---------- hgemm_n5: v; 2 node x 2 ch tiles/wave; 8 waves = 8 K-slices, LDS reduce ----------
__global__ __launch_bounds__(512) void k_hgemm_n5(const unsigned* __restrict__ hg,
                                                  const short* __restrict__ tbs2,
                                                  const float* __restrict__ dinvf,
                                                  const short* __restrict__ xp,
                                                  short* __restrict__ vb) {
  __shared__ float red[8][64][33];
  const int b = blockIdx.z;
  const int cbp = blockIdx.x;
  const int m0 = blockIdx.y * 64;
  const int ks = threadIdx.x >> 6;   // 8 K-slices of 512
  const int l = threadIdx.x & 63;
  const int col = l & 31, half = l >> 5;
  const int sh8 = half * 8;

  f32x16 acc00, acc01, acc10, acc11;
#pragma unroll
  for (int r = 0; r < 16; ++r) { acc00[r] = 0.f; acc01[r] = 0.f; acc10[r] = 0.f; acc11[r] = 0.f; }

  const short* pb0 = tbs2 + ((size_t)b << 20) + ((size_t)(cbp * 2) * 512 + half) * 256
                   + col * 8 + ks * 16384;
  const short* pb1 = pb0 + 131072;
  const uint4* hrow0 = (const uint4*)((const unsigned char*)hg
                     + ((size_t)b * NPIX + m0 + col) * 512 + ks * 64);
  const uint4* hrow1 = (const uint4*)((const unsigned char*)hg
                     + ((size_t)b * NPIX + m0 + 32 + col) * 512 + ks * 64);

#pragma unroll
  for (int o = 0; o < 4; ++o) {
    const uint4 wq0 = hrow0[o];
    const uint4 wq1 = hrow1[o];
    const unsigned ww0[4] = {wq0.x, wq0.y, wq0.z, wq0.w};
    const unsigned ww1[4] = {wq1.x, wq1.y, wq1.z, wq1.w};
#pragma unroll
    for (int s = 0; s < 4; ++s) {
      const bf16x8 b00 = *(const bf16x8*)(pb0);
      const bf16x8 b01 = *(const bf16x8*)(pb0 + 512);
      const bf16x8 b10 = *(const bf16x8*)(pb1);
      const bf16x8 b11 = *(const bf16x8*)(pb1 + 512);
      pb0 += 1024; pb1 += 1024;
      const bf16x8 a0 = byte2bf((ww0[s] >> sh8) & 0xFFu);
      const bf16x8 a1 = byte2bf((ww0[s] >> (16 + sh8)) & 0xFFu);
      const bf16x8 a2 = byte2bf((ww1[s] >> sh8) & 0xFFu);
      const bf16x8 a3 = byte2bf((ww1[s] >> (16 + sh8)) & 0xFFu);
      acc00 = __builtin_amdgcn_mfma_f32_32x32x16_bf16(a0, b00, acc00, 0, 0, 0);
      acc00 = __builtin_amdgcn_mfma_f32_32x32x16_bf16(a1, b01, acc00, 0, 0, 0);
      acc01 = __builtin_amdgcn_mfma_f32_32x32x16_bf16(a0, b10, acc01, 0, 0, 0);
      acc01 = __builtin_amdgcn_mfma_f32_32x32x16_bf16(a1, b11, acc01, 0, 0, 0);
      acc10 = __builtin_amdgcn_mfma_f32_32x32x16_bf16(a2, b00, acc10, 0, 0, 0);
      acc10 = __builtin_amdgcn_mfma_f32_32x32x16_bf16(a3, b01, acc10, 0, 0, 0);
      acc11 = __builtin_amdgcn_mfma_f32_32x32x16_bf16(a2, b10, acc11, 0, 0, 0);
      acc11 = __builtin_amdgcn_mfma_f32_32x32x16_bf16(a3, b11, acc11, 0, 0, 0);
    }
  }

  const short* xpb = xp + (size_t)b * NPIX * CH;
  // round A: node tile 0
#pragma unroll
  for (int r = 0; r < 16; ++r) { red[ks][l][r] = acc00[r]; red[ks][l][16 + r] = acc01[r]; }
  __syncthreads();
  {
    const int cc = cbp * 64 + col;
#pragma unroll
    for (int rj = 0; rj < 4; ++rj) {
      const int reg = ks * 4 + rj;
      float s = 0.f;
#pragma unroll
      for (int w = 0; w < 8; ++w) s += red[w][l][reg];
      const int rm = reg & 15;
      const int r = m0 + (rm & 3) + 8 * (rm >> 2) + 4 * half;
      const int ccc = cc + (reg < 16 ? 0 : 32);
      const size_t o = ((size_t)(b * NPIX + r)) * CH + ccc;
      vb[o] = f2b(s * dinvf[b * NPIX + r] + b2f(xpb[packoff(r, ccc)]));
    }
  }
  __syncthreads();
  // round B: node tile 1
#pragma unroll
  for (int r = 0; r < 16; ++r) { red[ks][l][r] = acc10[r]; red[ks][l][16 + r] = acc11[r]; }
  __syncthreads();
  {
    const int cc = cbp * 64 + col;
#pragma unroll
    for (int rj = 0; rj < 4; ++rj) {
      const int reg = ks * 4 + rj;
      float s = 0.f;
#pragma unroll
      for (int w = 0; w < 8; ++w) s += red[w][l][reg];
      const int rm = reg & 15;
      const int r = m0 + 32 + (rm & 3) + 8 * (rm >> 2) + 4 * half;
      const int ccc = cc + (reg < 16 ? 0 : 32);
      const size_t o = ((size_t)(b * NPIX + r)) * CH + ccc;
      vb[o] = f2b(s * dinvf[b * NPIX + r] + b2f(xpb[packoff(r, ccc)]));
    }
  }
}

// ---------- BN statistics (bf16 input) ----------
__global__ void k_bnstat(const short* __restrict__ vb, float* __restrict__ part) {
  const int t = threadIdx.x, blk = blockIdx.x;  // 128 blocks x 64 rows
  float s = 0.f, ss = 0.f;
  const short* p = vb + (size_t)blk * 64 * CH;
  for (int r = 0; r < 64; ++r) {
    const float v = b2f(p[r * CH + t]);
    s += v; ss += v * v;
  }
  part[blk * 512 + t] = s;
  part[blk * 512 + 256 + t] = ss;
}

__global__ void k_bnfin(const float* __restrict__ part, const float* __restrict__ gamma,
                        const float* __restrict__ beta, float* __restrict__ bnss) {
  const int t = threadIdx.x;  // 256
  float s = 0.f, ss = 0.f;
  for (int i = 0; i < 128; ++i) { s += part[i * 512 + t]; ss += part[i * 512 + 256 + t]; }
  const float mean = s * (1.f / 8192.f);
  const float var = ss * (1.f / 8192.f) - mean * mean;
  const float inv = rsqrtf(var + 1e-5f);
  const float sc = gamma[t] * inv;
  bnss[t] = sc;
  bnss[256 + t] = beta[t] - mean * sc;
}

// ---------- BN apply + SiLU (bf16 in) -> conv input pack ----------
__global__ void k_bnapply3(const short* __restrict__ vb, const float* __restrict__ bnss,
                           short* __restrict__ xpp) {
  const int i = blockIdx.x * 256 + threadIdx.x;  // 524288 short4 groups
  const short4 sv = reinterpret_cast<const short4*>(vb)[i];
  const int c0 = (i & 63) * 4;
  const int n = (i >> 6) & 4095;
  const int b = i >> 18;
  const float4 sc = *(const float4*)(bnss + c0);
  const float4 sh = *(const float4*)(bnss + 256 + c0);
  const float u0 = b2f(sv.x) * sc.x + sh.x;
  const float u1 = b2f(sv.y) * sc.y + sh.y;
  const float u2 = b2f(sv.z) * sc.z + sh.z;
  const float u3 = b2f(sv.w) * sc.w + sh.w;
  short4 o;
  o.x = f2b(u0 / (1.f + expf(-u0)));
  o.y = f2b(u1 / (1.f + expf(-u1)));
  o.z = f2b(u2 / (1.f + expf(-u2)));
  o.w = f2b(u3 / (1.f + expf(-u3)));
  const int ih = n >> 6, iw = n & 63;
  const int p = iw & 1, ow = iw >> 1;
  const size_t off = ((size_t)(((b * 2 + p) * 64 + ih) * 16 + (c0 >> 4)) * 2 + ((c0 >> 3) & 1)) * 256
                   + ow * 8 + (c0 & 7);
  *(short4*)(xpp + off) = o;
}

// ---------- 3x3 stride-2 conv via packed MFMA, channel-split 4-way ----------
__global__ __launch_bounds__(64) void k_conv5(const short* __restrict__ xpp,
                                              const short* __restrict__ w3p,
                                              float* __restrict__ convp) {
  const int ocg = blockIdx.x;
  const int oh = blockIdx.y;
  const int bz = blockIdx.z;    // cs*2 + b (8)
  const int b = bz & 1, cs = bz >> 1;
  const int l = threadIdx.x;
  const int col = l & 31;
  const bf16x8 zv = {0, 0, 0, 0, 0, 0, 0, 0};

  f32x16 acc;
#pragma unroll
  for (int r = 0; r < 16; ++r) acc[r] = 0.f;

  for (int kh = 0; kh < 3; ++kh) {
    const int ih = 2 * oh + kh;
    if (ih >= 64) continue;
#pragma unroll
    for (int kw = 0; kw < 3; ++kw) {
      const int p = kw & 1;
      const short* pa = xpp + ((size_t)((b * 2 + p) * 64 + ih) * 16 + cs * 4) * 512
                      + l * 8 + (kw == 2 ? 8 : 0);
      const short* pb = w3p + ((size_t)((kh * 3 + kw) * 8 + ocg) * 16 + cs * 4) * 512 + l * 8;
      const bool kill = (kw == 2) && (col == 31);
#pragma unroll
      for (int kb = 0; kb < 4; ++kb) {
        bf16x8 a = *(const bf16x8*)(pa + kb * 512);
        if (kill) a = zv;
        const bf16x8 bb = *(const bf16x8*)(pb + kb * 512);
        acc = __builtin_amdgcn_mfma_f32_32x32x16_bf16(a, bb, acc, 0, 0, 0);
      }
    }
  }
  const int half = l >> 5;
  const int oc = ocg * 32 + col;
#pragma unroll
  for (int q = 0; q < 4; ++q)
#pragma unroll
    for (int rr = 0; rr < 4; ++rr) {
      const int ow = rr + 8 * q + 4 * half;
      convp[((size_t)bz * 1024 + oh * 32 + ow) * 256 + oc] = acc[q * 4 + rr];
    }
}

// ---------- merge conv quarters + bias -> packed bf16 xdtb ----------
__global__ void k_convmerge3(const float* __restrict__ convp, const float* __restrict__ db,
                             short* __restrict__ xdtb) {
  const int i = blockIdx.x * 256 + threadIdx.x;  // 131072 groups of 4
  const int b = i >> 16, px = (i >> 6) & 1023, oc0 = (i & 63) * 4;
  const size_t base = ((size_t)px) * 256 + oc0;
  const float4 h0 = *(const float4*)(convp + ((size_t)(0 + b) << 18) + base);
  const float4 h1 = *(const float4*)(convp + ((size_t)(2 + b) << 18) + base);
  const float4 h2 = *(const float4*)(convp + ((size_t)(4 + b) << 18) + base);
  const float4 h3 = *(const float4*)(convp + ((size_t)(6 + b) << 18) + base);
  const float4 bv = *(const float4*)(db + oc0);
  short4 o;
  o.x = f2b(h0.x + h1.x + h2.x + h3.x + bv.x);
  o.y = f2b(h0.y + h1.y + h2.y + h3.y + bv.y);
  o.z = f2b(h0.z + h1.z + h2.z + h3.z + bv.z);
  o.w = f2b(h0.w + h1.w + h2.w + h3.w + bv.w);
  const size_t off = ((size_t)((b * 32 + (px >> 5)) * 16 + (oc0 >> 4)) * 2 + ((oc0 >> 3) & 1)) * 256
                   + (px & 31) * 8 + (oc0 & 7);
  *(short4*)(xdtb + off) = o;
}

// ---------- final 1x1 GEMM on packed operands, f32 out + row bias ----------
__global__ __launch_bounds__(256) void k_mfma_nt2(const short* __restrict__ woutp,
                                                  const short* __restrict__ xdtb,
                                                  float* __restrict__ C,
                                                  const float* __restrict__ bias) {
  const int b = blockIdx.z;
  xdtb += (size_t)b * 1024 * CH;
  C += (size_t)b * 512 * 1024;
  const int t = threadIdx.x, l = t & 63, wid = t >> 6;
  const int m0 = blockIdx.y * 128 + wid * 32, n0 = blockIdx.x * 64;
  const int col = l & 31, half = l >> 5;
  f32x16 acc[2];
#pragma unroll
  for (int nt = 0; nt < 2; ++nt)
#pragma unroll
    for (int r = 0; r < 16; ++r) acc[nt][r] = 0.f;
  const short* pa = woutp + (size_t)(m0 >> 5) * 8192 + l * 8;
  const short* pb = xdtb + (size_t)(n0 >> 5) * 8192 + l * 8;
#pragma unroll 4
  for (int kb = 0; kb < 16; ++kb) {
    const bf16x8 a = *(const bf16x8*)(pa + kb * 512);
    const bf16x8 b0 = *(const bf16x8*)(pb + kb * 512);
    const bf16x8 b1 = *(const bf16x8*)(pb + 8192 + kb * 512);
    acc[0] = __builtin_amdgcn_mfma_f32_32x32x16_bf16(a, b0, acc[0], 0, 0, 0);
    acc[1] = __builtin_amdgcn_mfma_f32_32x32x16_bf16(a, b1, acc[1], 0, 0, 0);
  }
#pragma unroll
  for (int nt = 0; nt < 2; ++nt) {
#pragma unroll
    for (int q = 0; q < 4; ++q)
#pragma unroll
      for (int rr = 0; rr < 4; ++rr) {
        const int row = m0 + rr + 8 * q + 4 * half;
        const int cc = n0 + nt * 32 + col;
        C[(size_t)row * 1024 + cc] = acc[nt][q * 4 + rr] + bias[row];
      }
  }
}

extern "C" void kernel_launch(void* const* d_in, const int* in_sizes, int n_in,
                              void* d_out, int out_size, void* d_ws, size_t ws_size,
                              hipStream_t stream) {
  const float* x     = (const float*)d_in[0];
  const float* fc_w  = (const float*)d_in[1];
  const float* fc_b  = (const float*)d_in[2];
  const float* gamma = (const float*)d_in[3];
  const float* beta  = (const float*)d_in[4];
  const float* dw    = (const float*)d_in[5];
  const float* db    = (const float*)d_in[6];
  const float* ow    = (const float*)d_in[7];
  const float* ob    = (const float*)d_in[8];

  float* ws   = (float*)d_ws;
  short* xp   = (short*)(ws + OFF_XP);
  float* convp= ws + OFF_XP;              // 8 MB: XP+XR (both dead after hgemm_n5)
  short* vb   = (short*)(ws + OFF_VB);
  short* tbs  = (short*)(ws + OFF_TBS);   // y^T; later xdtb
  short* xdtb = (short*)(ws + OFF_TBS);
  short* tbs2 = (short*)(ws + OFF_TBS2);  // E^T; later xpp
  short* xpp  = (short*)(ws + OFF_TBS2);
  unsigned* hg = (unsigned*)(ws + OFF_HG);
  float* sqv  = ws + OFF_SQ;
  float* part = ws + OFF_PART;
  float* bnss = ws + OFF_BNSS;
  float* dinvf= ws + OFF_DINV;
  short* w3p  = (short*)(ws + OFF_W3P);
  short* wfcp = (short*)(ws + OFF_WFCP);
  short* woutp= (short*)(ws + OFF_WOUTP);
  float* out  = (float*)d_out;

  // fused: transpose+pack+sq (256 blocks) | weight packs (3072 blocks)
  k_front2<<<3328, 256, 0, stream>>>(x, xp, sqv, fc_w, ow, dw, wfcp, woutp, w3p);
  // Gram: triangular 128x128 blocks (2 waves), writes upper + mirrored words directly
  k_gram4<<<dim3(528, 1, 2), 128, 0, stream>>>(xp, sqv, hg);
  // fused: fc GEMM (256 blocks) | 1/deg (2048 blocks)
  k_fcdinv<<<2304, 256, 0, stream>>>(wfcp, xp, tbs, fc_b, hg, dinvf);
  // E^T: 8-wave blocks, K-split-8 across waves, LDS reduce + dinv
  k_hgemm_t5<<<dim3(64, 4, 2), 512, 0, stream>>>(tbs, hg, dinvf, tbs2);
  // v: 8-wave blocks, K-split-8 across waves, LDS reduce + dinv + residual
  k_hgemm_n5<<<dim3(4, 64, 2), 512, 0, stream>>>(hg, tbs2, dinvf, xp, vb);
  // BN + SiLU -> conv input pack
  k_bnstat<<<128, 256, 0, stream>>>(vb, part);
  k_bnfin<<<1, 256, 0, stream>>>(part, gamma, beta, bnss);
  k_bnapply3<<<2048, 256, 0, stream>>>(vb, bnss, xpp);
  // 3x3 s2 conv (packed MFMA, K split 4-way) -> f32 partials -> packed bf16
  k_conv5<<<dim3(8, 32, 8), 64, 0, stream>>>(xpp, w3p, convp);
  k_convmerge3<<<512, 256, 0, stream>>>(convp, db, xdtb);
  // out = out_w @ xdT^T + out_b
  k_mfma_nt2<<<dim3(16, 4, 2), 256, 0, stream>>>(woutp, xdtb, out, ob);
}

// Round 18
// 130.208 us; speedup vs baseline: 1.0785x; 1.0183x over previous
//
#include <hip/hip_runtime.h>
#include <hip/hip_bf16.h>
#include <math.h>

#define NPIX 4096
#define CH   256

// ---- ws float offsets ----
#define OFF_XP    0u         // bf16 packed x; later convp f32 [8][1024][256] (spans XP+XR)
#define OFF_XR    1048576u   // (free; convp upper half)
#define OFF_VB    2097152u   // bf16 v [2][4096][256] (BN input)
#define OFF_TBS   3145728u   // bf16 swizzled y^T; later xdtb pack
#define OFF_TBS2  4194304u   // bf16 swizzled E^T; later xpp conv input pack
#define OFF_HG    5242880u   // uint32 [2][4096][128] incidence bitmask
#define OFF_SQ    6291456u   // [8192] f32
#define OFF_PART  6299648u   // [128][512] f32 BN partials
#define OFF_BNSS  6365184u   // [512] f32
#define OFF_DINV  6365696u   // [8192] f32 1/deg
#define OFF_W3P   6373888u   // bf16 [9tap][8ocR][16kb][2h][32][8]
#define OFF_WFCP  6668800u   // bf16 packed fc_w
#define OFF_WOUTP 6701568u   // bf16 packed out_w
// end: 6767104 floats = 27.1 MB

typedef __attribute__((ext_vector_type(8))) short bf16x8;
typedef __attribute__((ext_vector_type(16))) float f32x16;

static __device__ __forceinline__ short f2b(float f) {
  __hip_bfloat16 h = __float2bfloat16(f);
  return *reinterpret_cast<short*>(&h);
}
static __device__ __forceinline__ float b2f(short s) {
  union { unsigned u; float f; } r;
  r.u = ((unsigned)(unsigned short)s) << 16;
  return r.f;
}

// expand 8 incidence bits (byte) -> bf16x8 of {0,1}  (pure VALU)
static __device__ __forceinline__ bf16x8 byte2bf(unsigned byte) {
  union { unsigned u[4]; bf16x8 h; } r;
  r.u[0] = ((byte * 0x8001u) & 0x10001u) * 0x3F80u;
  r.u[1] = (((byte >> 2) * 0x8001u) & 0x10001u) * 0x3F80u;
  r.u[2] = (((byte >> 4) * 0x8001u) & 0x10001u) * 0x3F80u;
  r.u[3] = (((byte >> 6) * 0x8001u) & 0x10001u) * 0x3F80u;
  return r.h;
}

// pack offset for element (row m, k c), K=256: [m>>5][c>>4][(c>>3)&1][m&31][c&7]
static __device__ __forceinline__ size_t packoff(int m, int c) {
  return ((size_t)((m >> 5) * 16 + (c >> 4)) * 2 + ((c >> 3) & 1)) * 256 + (m & 31) * 8 + (c & 7);
}

// ---------- fused front-end: transpose+pack+sq (blocks 0-255) | weight packers (256+) ----------
__global__ __launch_bounds__(256) void k_front2(const float* __restrict__ x,
                                                short* __restrict__ xp,
                                                float* __restrict__ sq,
                                                const float* __restrict__ fc_w,
                                                const float* __restrict__ ow,
                                                const float* __restrict__ dw,
                                                short* __restrict__ wfcp,
                                                short* __restrict__ woutp,
                                                short* __restrict__ w3p) {
  __shared__ float lds[256][33];
  __shared__ float red2[8][32];
  const int bid = blockIdx.x;
  const int t = threadIdx.x;
  if (bid < 256) {
    const int b = bid >> 7;
    const int n0 = (bid & 127) * 32;
    const float* xb = x + (size_t)b * CH * NPIX + n0;
    const int j = t & 31, cg8 = t >> 5;
#pragma unroll 4
    for (int it = 0; it < 32; ++it) {
      const int c = it * 8 + cg8;
      lds[c][j] = xb[(size_t)c * NPIX + j];
    }
    __syncthreads();
    {
      const int n = t & 31, cg = t >> 5;
      float s = 0.f;
#pragma unroll 8
      for (int i = 0; i < 32; ++i) {
        const float v = lds[cg * 32 + i][n];
        s += v * v;
      }
      red2[cg][n] = s;
    }
    short* xpb = xp + (size_t)b * NPIX * CH;
#pragma unroll
    for (int i = 0; i < 4; ++i) {
      const int f = i * 256 + t;
      const int n = f & 31, c0 = (f >> 5) * 8;
      short tmp[8];
#pragma unroll
      for (int k = 0; k < 8; ++k) tmp[k] = f2b(lds[c0 + k][n]);
      short* dst = xpb + packoff(n0 + n, c0);
      *(short4*)dst = *(short4*)&tmp[0];
      *(short4*)(dst + 4) = *(short4*)&tmp[4];
    }
    __syncthreads();
    if (t < 32) {
      float s = 0.f;
#pragma unroll
      for (int cg = 0; cg < 8; ++cg) s += red2[cg][t];
      sq[b * NPIX + n0 + t] = s;
    }
  } else {
    const int i = (bid - 256) * 256 + t;  // 786432
    if (i < 65536) {
      wfcp[packoff(i >> 8, i & 255)] = f2b(fc_w[i]);
    } else if (i < 196608) {
      const int j = i - 65536;
      woutp[packoff(j >> 8, j & 255)] = f2b(ow[j]);
    } else {
      const int j = i - 196608;        // dw[oc][c][kh][kw]
      const int oc = j / 2304;
      const int rem = j % 2304;
      const int c = rem / 9, tap = rem % 9;
      const size_t off = ((size_t)((tap * 8 + (oc >> 5)) * 16 + (c >> 4)) * 2 + ((c >> 3) & 1)) * 256
                       + (oc & 31) * 8 + (c & 7);
      w3p[off] = f2b(dw[j]);
    }
  }
}

// ---------- Gram: triangular 128x128 blocks (2 waves x 64x128), upper + mirrored writes ----------
__global__ __launch_bounds__(128, 2) void k_gram4(const short* __restrict__ xp,
                                                  const float* __restrict__ sq,
                                                  unsigned* __restrict__ hgbit) {
  const int b = blockIdx.z;
  int tt = blockIdx.x;
  int bi = (int)((65.0f - sqrtf(4225.0f - 8.0f * (float)tt)) * 0.5f);
  bi = bi < 0 ? 0 : (bi > 31 ? 31 : bi);
  while (bi * (65 - bi) / 2 > tt) --bi;
  while ((bi + 1) * (64 - bi) / 2 <= tt) ++bi;
  const int bj = bi + (tt - bi * (65 - bi) / 2);
  const int i0 = bi * 128, j0 = bj * 128;

  const int t = threadIdx.x;
  const int lane = t & 63, w = t >> 6;
  const int c = lane & 31, h = lane >> 5;
  const short* xb = xp + (size_t)b * NPIX * CH;
  const int ibase = i0 + w * 64;
  const int jbase = j0;

  f32x16 acc[2][4];
#pragma unroll
  for (int m = 0; m < 2; ++m)
#pragma unroll
    for (int n = 0; n < 4; ++n)
#pragma unroll
      for (int r = 0; r < 16; ++r) acc[m][n][r] = 0.f;

  const short* pa = xb + (size_t)(ibase >> 5) * 8192 + lane * 8;
  const short* pb = xb + (size_t)(jbase >> 5) * 8192 + lane * 8;

#pragma unroll 2
  for (int kb = 0; kb < 16; ++kb) {
    const bf16x8 a0 = *(const bf16x8*)(pa + kb * 512);
    const bf16x8 a1 = *(const bf16x8*)(pa + 8192 + kb * 512);
    bf16x8 bb[4];
#pragma unroll
    for (int n = 0; n < 4; ++n) bb[n] = *(const bf16x8*)(pb + (size_t)n * 8192 + kb * 512);
#pragma unroll
    for (int n = 0; n < 4; ++n) {
      acc[0][n] = __builtin_amdgcn_mfma_f32_32x32x16_bf16(a0, bb[n], acc[0][n], 0, 0, 0);
      acc[1][n] = __builtin_amdgcn_mfma_f32_32x32x16_bf16(a1, bb[n], acc[1][n], 0, 0, 0);
    }
  }

  const int sqb = b * NPIX;
#pragma unroll
  for (int m = 0; m < 2; ++m) {
    float4 sqa[4];
#pragma unroll
    for (int q = 0; q < 4; ++q)
      sqa[q] = *(const float4*)(sq + sqb + ibase + m * 32 + q * 8 + 4 * h);
#pragma unroll
    for (int n = 0; n < 4; ++n) {
      const float sj = sq[sqb + jbase + n * 32 + c];
      const int wj = (jbase + n * 32) >> 5;
      unsigned mmask = 0u;
#pragma unroll
      for (int q = 0; q < 4; ++q) {
        const float sqq[4] = {sqa[q].x, sqa[q].y, sqa[q].z, sqa[q].w};
#pragma unroll
        for (int rr = 0; rr < 4; ++rr) {
          const int reg = q * 4 + rr;
          const float d2 = sqq[rr] + sj - 2.f * acc[m][n][reg];
          const bool cond = d2 < 100.f;
          const unsigned long long bal = __ballot(cond);
          if ((lane & 31) == reg) {
            const int row = ibase + m * 32 + rr + 8 * q + 4 * h;
            const unsigned wd = h ? (unsigned)(bal >> 32) : (unsigned)bal;
            hgbit[(size_t)(sqb + row) * 128 + wj] = wd;
          }
          mmask |= (cond ? 1u : 0u) << (rr + 8 * q + 4 * h);
        }
      }
      const unsigned merged = mmask | (unsigned)__shfl_xor((int)mmask, 32, 64);
      if (h == 0) {
        const int colg = jbase + n * 32 + c;
        hgbit[(size_t)(sqb + colg) * 128 + ((ibase + m * 32) >> 5)] = merged;
      }
    }
  }
}

// ---------- fc GEMM (blocks 0-255) | 1/deg (blocks 256+) ----------
__global__ __launch_bounds__(256) void k_fcdinv(const short* __restrict__ wfcp,
                                                const short* __restrict__ xp,
                                                short* __restrict__ C,
                                                const float* __restrict__ bias,
                                                const unsigned* __restrict__ hg,
                                                float* __restrict__ dinvf) {
  const int bid = blockIdx.x;
  const int t = threadIdx.x;
  if (bid >= 256) {
    const int row = (bid - 256) * 4 + (t >> 6);
    const int l = t & 63;
    const unsigned w0 = hg[(size_t)row * 128 + l * 2];
    const unsigned w1 = hg[(size_t)row * 128 + l * 2 + 1];
    int n = __popc(w0) + __popc(w1);
#pragma unroll
    for (int off = 32; off; off >>= 1) n += __shfl_down(n, off);
    if (l == 0) dinvf[row] = 1.0f / (float)n;
    return;
  }
  const int b = bid >> 7;
  const short* xpb = xp + (size_t)b * NPIX * CH;
  short* Cb = C + ((size_t)b << 20);
  const int l = t & 63, wid = t >> 6;
  const int m0 = ((bid >> 6) & 1) * 128 + wid * 32, n0 = (bid & 63) * 64;
  const int col = l & 31, half = l >> 5;
  f32x16 acc[2];
#pragma unroll
  for (int nt = 0; nt < 2; ++nt)
#pragma unroll
    for (int r = 0; r < 16; ++r) acc[nt][r] = 0.f;
  const short* pa = wfcp + (size_t)(m0 >> 5) * 8192 + l * 8;
  const short* pb = xpb + (size_t)(n0 >> 5) * 8192 + l * 8;
#pragma unroll 4
  for (int kb = 0; kb < 16; ++kb) {
    const bf16x8 a = *(const bf16x8*)(pa + kb * 512);
    const bf16x8 b0 = *(const bf16x8*)(pb + kb * 512);
    const bf16x8 b1 = *(const bf16x8*)(pb + 8192 + kb * 512);
    acc[0] = __builtin_amdgcn_mfma_f32_32x32x16_bf16(a, b0, acc[0], 0, 0, 0);
    acc[1] = __builtin_amdgcn_mfma_f32_32x32x16_bf16(a, b1, acc[1], 0, 0, 0);
  }
  const int cb = m0 >> 5;
#pragma unroll
  for (int nt = 0; nt < 2; ++nt) {
    const int node = n0 + nt * 32 + col;
    short* dst = Cb + ((size_t)cb * 512 + (node >> 3)) * 256 + (node & 7);
#pragma unroll
    for (int q = 0; q < 4; ++q)
#pragma unroll
      for (int rr = 0; rr < 4; ++rr) {
        const int c31 = rr + 8 * q + 4 * half;
        dst[c31 * 8] = f2b(acc[nt][q * 4 + rr] + bias[m0 + c31]);
      }
  }
}

// ---------- hgemm_t5: E^T; XCD-pinned 1D grid; 8 waves = 8 K-slices, LDS reduce ----------
__global__ __launch_bounds__(512) void k_hgemm_t5(const short* __restrict__ tbs,
                                                  const unsigned* __restrict__ hg,
                                                  const float* __restrict__ dinvf,
                                                  short* __restrict__ tbs2) {
  __shared__ float red[8][64][33];
  // XCD pinning: id%8 == cbp + 4*b (round-robin dispatch) -> each (cbp,b) slice on one XCD
  const int id = blockIdx.x;
  const int cbp = id & 3;
  const int b = (id >> 2) & 1;
  const int n0 = (id >> 3) * 64;
  const int ks = threadIdx.x >> 6;   // 8 K-slices of 512
  const int l = threadIdx.x & 63;
  const int col = l & 31, half = l >> 5;
  const int sh8 = half * 8;

  f32x16 acc00, acc01, acc10, acc11;
#pragma unroll
  for (int r = 0; r < 16; ++r) { acc00[r] = 0.f; acc01[r] = 0.f; acc10[r] = 0.f; acc11[r] = 0.f; }

  const short* pa0 = tbs + ((size_t)b << 20) + ((size_t)(cbp * 2) * 512 + half) * 256
                   + col * 8 + ks * 16384;
  const short* pa1 = pa0 + 131072;
  const uint4* hrow0 = (const uint4*)((const unsigned char*)hg
                     + ((size_t)b * NPIX + n0 + col) * 512 + ks * 64);
  const uint4* hrow1 = (const uint4*)((const unsigned char*)hg
                     + ((size_t)b * NPIX + n0 + 32 + col) * 512 + ks * 64);

#pragma unroll
  for (int o = 0; o < 4; ++o) {
    const uint4 wq0 = hrow0[o];
    const uint4 wq1 = hrow1[o];
    const unsigned ww0[4] = {wq0.x, wq0.y, wq0.z, wq0.w};
    const unsigned ww1[4] = {wq1.x, wq1.y, wq1.z, wq1.w};
#pragma unroll
    for (int s = 0; s < 4; ++s) {
      const bf16x8 a00 = *(const bf16x8*)(pa0);
      const bf16x8 a01 = *(const bf16x8*)(pa0 + 512);
      const bf16x8 a10 = *(const bf16x8*)(pa1);
      const bf16x8 a11 = *(const bf16x8*)(pa1 + 512);
      pa0 += 1024; pa1 += 1024;
      const bf16x8 b0 = byte2bf((ww0[s] >> sh8) & 0xFFu);
      const bf16x8 b1 = byte2bf((ww0[s] >> (16 + sh8)) & 0xFFu);
      const bf16x8 c0 = byte2bf((ww1[s] >> sh8) & 0xFFu);
      const bf16x8 c1 = byte2bf((ww1[s] >> (16 + sh8)) & 0xFFu);
      acc00 = __builtin_amdgcn_mfma_f32_32x32x16_bf16(a00, b0, acc00, 0, 0, 0);
      acc00 = __builtin_amdgcn_mfma_f32_32x32x16_bf16(a01, b1, acc00, 0, 0, 0);
      acc10 = __builtin_amdgcn_mfma_f32_32x32x16_bf16(a10, b0, acc10, 0, 0, 0);
      acc10 = __builtin_amdgcn_mfma_f32_32x32x16_bf16(a11, b1, acc10, 0, 0, 0);
      acc01 = __builtin_amdgcn_mfma_f32_32x32x16_bf16(a00, c0, acc01, 0, 0, 0);
      acc01 = __builtin_amdgcn_mfma_f32_32x32x16_bf16(a01, c1, acc01, 0, 0, 0);
      acc11 = __builtin_amdgcn_mfma_f32_32x32x16_bf16(a10, c0, acc11, 0, 0, 0);
      acc11 = __builtin_amdgcn_mfma_f32_32x32x16_bf16(a11, c1, acc11, 0, 0, 0);
    }
  }

  // round A: node tile 0 (acc00=cb0, acc10=cb1)
#pragma unroll
  for (int r = 0; r < 16; ++r) { red[ks][l][r] = acc00[r]; red[ks][l][16 + r] = acc10[r]; }
  __syncthreads();
  {
    const int n = n0 + col;
    const float dinv = dinvf[b * NPIX + n];
    short* dst0 = tbs2 + ((size_t)b << 20) + ((size_t)(cbp * 2) * 512 + (n >> 3)) * 256 + (n & 7);
    short* dst1 = dst0 + 131072;
#pragma unroll
    for (int rj = 0; rj < 4; ++rj) {
      const int reg = ks * 4 + rj;
      float s = 0.f;
#pragma unroll
      for (int w = 0; w < 8; ++w) s += red[w][l][reg];
      const int rm = reg & 15;
      const int c31 = (rm & 3) + 8 * (rm >> 2) + 4 * half;
      (reg < 16 ? dst0 : dst1)[c31 * 8] = f2b(s * dinv);
    }
  }
  __syncthreads();
  // round B: node tile 1 (acc01=cb0, acc11=cb1)
#pragma unroll
  for (int r = 0; r < 16; ++r) { red[ks][l][r] = acc01[r]; red[ks][l][16 + r] = acc11[r]; }
  __syncthreads();
  {
    const int n = n0 + 32 + col;
    const float dinv = dinvf[b * NPIX + n];
    short* dst0 = tbs2 + ((size_t)b << 20) + ((size_t)(cbp * 2) * 512 + (n >> 3)) * 256 + (n & 7);
    short* dst1 = dst0 + 131072;
#pragma unroll
    for (int rj = 0; rj < 4; ++rj) {
      const int reg = ks * 4 + rj;
      float s = 0.f;
#pragma unroll
      for (int w = 0; w < 8; ++w) s += red[w][l][reg];
      const int rm = reg & 15;
      const int c31 = (rm & 3) + 8 * (rm >> 2) + 4 * half;
      (reg < 16 ? dst0 : dst1)[c31 * 8] = f2b(s * dinv);
    }
  }
}

// ---------- hgemm_n5: v; XCD-pinned 1D grid; 8 waves = 8 K-slices, LDS reduce ----------
__global__ __launch_bounds__(512) void k_hgemm_n5(const unsigned* __restrict__ hg,
                                                  const short* __restrict__ tbs2,
                                                  const float* __restrict__ dinvf,
                                                  const short* __restrict__ xp,
                                                  short* __restrict__ vb) {
  __shared__ float red[8][64][33];
  const int id = blockIdx.x;
  const int cbp = id & 3;
  const int b = (id >> 2) & 1;
  const int m0 = (id >> 3) * 64;
  const int ks = threadIdx.x >> 6;   // 8 K-slices of 512
  const int l = threadIdx.x & 63;
  const int col = l & 31, half = l >> 5;
  const int sh8 = half * 8;

  f32x16 acc00, acc01, acc10, acc11;
#pragma unroll
  for (int r = 0; r < 16; ++r) { acc00[r] = 0.f; acc01[r] = 0.f; acc10[r] = 0.f; acc11[r] = 0.f; }

  const short* pb0 = tbs2 + ((size_t)b << 20) + ((size_t)(cbp * 2) * 512 + half) * 256
                   + col * 8 + ks * 16384;
  const short* pb1 = pb0 + 131072;
  const uint4* hrow0 = (const uint4*)((const unsigned char*)hg
                     + ((size_t)b * NPIX + m0 + col) * 512 + ks * 64);
  const uint4* hrow1 = (const uint4*)((const unsigned char*)hg
                     + ((size_t)b * NPIX + m0 + 32 + col) * 512 + ks * 64);

#pragma unroll
  for (int o = 0; o < 4; ++o) {
    const uint4 wq0 = hrow0[o];
    const uint4 wq1 = hrow1[o];
    const unsigned ww0[4] = {wq0.x, wq0.y, wq0.z, wq0.w};
    const unsigned ww1[4] = {wq1.x, wq1.y, wq1.z, wq1.w};
#pragma unroll
    for (int s = 0; s < 4; ++s) {
      const bf16x8 b00 = *(const bf16x8*)(pb0);
      const bf16x8 b01 = *(const bf16x8*)(pb0 + 512);
      const bf16x8 b10 = *(const bf16x8*)(pb1);
      const bf16x8 b11 = *(const bf16x8*)(pb1 + 512);
      pb0 += 1024; pb1 += 1024;
      const bf16x8 a0 = byte2bf((ww0[s] >> sh8) & 0xFFu);
      const bf16x8 a1 = byte2bf((ww0[s] >> (16 + sh8)) & 0xFFu);
      const bf16x8 a2 = byte2bf((ww1[s] >> sh8) & 0xFFu);
      const bf16x8 a3 = byte2bf((ww1[s] >> (16 + sh8)) & 0xFFu);
      acc00 = __builtin_amdgcn_mfma_f32_32x32x16_bf16(a0, b00, acc00, 0, 0, 0);
      acc00 = __builtin_amdgcn_mfma_f32_32x32x16_bf16(a1, b01, acc00, 0, 0, 0);
      acc01 = __builtin_amdgcn_mfma_f32_32x32x16_bf16(a0, b10, acc01, 0, 0, 0);
      acc01 = __builtin_amdgcn_mfma_f32_32x32x16_bf16(a1, b11, acc01, 0, 0, 0);
      acc10 = __builtin_amdgcn_mfma_f32_32x32x16_bf16(a2, b00, acc10, 0, 0, 0);
      acc10 = __builtin_amdgcn_mfma_f32_32x32x16_bf16(a3, b01, acc10, 0, 0, 0);
      acc11 = __builtin_amdgcn_mfma_f32_32x32x16_bf16(a2, b10, acc11, 0, 0, 0);
      acc11 = __builtin_amdgcn_mfma_f32_32x32x16_bf16(a3, b11, acc11, 0, 0, 0);
    }
  }

  const short* xpb = xp + (size_t)b * NPIX * CH;
  // round A: node tile 0
#pragma unroll
  for (int r = 0; r < 16; ++r) { red[ks][l][r] = acc00[r]; red[ks][l][16 + r] = acc01[r]; }
  __syncthreads();
  {
    const int cc = cbp * 64 + col;
#pragma unroll
    for (int rj = 0; rj < 4; ++rj) {
      const int reg = ks * 4 + rj;
      float s = 0.f;
#pragma unroll
      for (int w = 0; w < 8; ++w) s += red[w][l][reg];
      const int rm = reg & 15;
      const int r = m0 + (rm & 3) + 8 * (rm >> 2) + 4 * half;
      const int ccc = cc + (reg < 16 ? 0 : 32);
      const size_t o = ((size_t)(b * NPIX + r)) * CH + ccc;
      vb[o] = f2b(s * dinvf[b * NPIX + r] + b2f(xpb[packoff(r, ccc)]));
    }
  }
  __syncthreads();
  // round B: node tile 1
#pragma unroll
  for (int r = 0; r < 16; ++r) { red[ks][l][r] = acc10[r]; red[ks][l][16 + r] = acc11[r]; }
  __syncthreads();
  {
    const int cc = cbp * 64 + col;
#pragma unroll
    for (int rj = 0; rj < 4; ++rj) {
      const int reg = ks * 4 + rj;
      float s = 0.f;
#pragma unroll
      for (int w = 0; w < 8; ++w) s += red[w][l][reg];
      const int rm = reg & 15;
      const int r = m0 + 32 + (rm & 3) + 8 * (rm >> 2) + 4 * half;
      const int ccc = cc + (reg < 16 ? 0 : 32);
      const size_t o = ((size_t)(b * NPIX + r)) * CH + ccc;
      vb[o] = f2b(s * dinvf[b * NPIX + r] + b2f(xpb[packoff(r, ccc)]));
    }
  }
}

// ---------- BN statistics (bf16 input) ----------
__global__ void k_bnstat(const short* __restrict__ vb, float* __restrict__ part) {
  const int t = threadIdx.x, blk = blockIdx.x;  // 128 blocks x 64 rows
  float s = 0.f, ss = 0.f;
  const short* p = vb + (size_t)blk * 64 * CH;
  for (int r = 0; r < 64; ++r) {
    const float v = b2f(p[r * CH + t]);
    s += v; ss += v * v;
  }
  part[blk * 512 + t] = s;
  part[blk * 512 + 256 + t] = ss;
}

__global__ void k_bnfin(const float* __restrict__ part, const float* __restrict__ gamma,
                        const float* __restrict__ beta, float* __restrict__ bnss) {
  const int t = threadIdx.x;  // 256
  float s = 0.f, ss = 0.f;
  for (int i = 0; i < 128; ++i) { s += part[i * 512 + t]; ss += part[i * 512 + 256 + t]; }
  const float mean = s * (1.f / 8192.f);
  const float var = ss * (1.f / 8192.f) - mean * mean;
  const float inv = rsqrtf(var + 1e-5f);
  const float sc = gamma[t] * inv;
  bnss[t] = sc;
  bnss[256 + t] = beta[t] - mean * sc;
}

// ---------- BN apply + SiLU (bf16 in) -> conv input pack ----------
__global__ void k_bnapply3(const short* __restrict__ vb, const float* __restrict__ bnss,
                           short* __restrict__ xpp) {
  const int i = blockIdx.x * 256 + threadIdx.x;  // 524288 short4 groups
  const short4 sv = reinterpret_cast<const short4*>(vb)[i];
  const int c0 = (i & 63) * 4;
  const int n = (i >> 6) & 4095;
  const int b = i >> 18;
  const float4 sc = *(const float4*)(bnss + c0);
  const float4 sh = *(const float4*)(bnss + 256 + c0);
  const float u0 = b2f(sv.x) * sc.x + sh.x;
  const float u1 = b2f(sv.y) * sc.y + sh.y;
  const float u2 = b2f(sv.z) * sc.z + sh.z;
  const float u3 = b2f(sv.w) * sc.w + sh.w;
  short4 o;
  o.x = f2b(u0 / (1.f + expf(-u0)));
  o.y = f2b(u1 / (1.f + expf(-u1)));
  o.z = f2b(u2 / (1.f + expf(-u2)));
  o.w = f2b(u3 / (1.f + expf(-u3)));
  const int ih = n >> 6, iw = n & 63;
  const int p = iw & 1, ow = iw >> 1;
  const size_t off = ((size_t)(((b * 2 + p) * 64 + ih) * 16 + (c0 >> 4)) * 2 + ((c0 >> 3) & 1)) * 256
                   + ow * 8 + (c0 & 7);
  *(short4*)(xpp + off) = o;
}

// ---------- 3x3 stride-2 conv via packed MFMA, channel-split 4-way ----------
__global__ __launch_bounds__(64) void k_conv5(const short* __restrict__ xpp,
                                              const short* __restrict__ w3p,
                                              float* __restrict__ convp) {
  const int ocg = blockIdx.x;
  const int oh = blockIdx.y;
  const int bz = blockIdx.z;    // cs*2 + b (8)
  const int b = bz & 1, cs = bz >> 1;
  const int l = threadIdx.x;
  const int col = l & 31;
  const bf16x8 zv = {0, 0, 0, 0, 0, 0, 0, 0};

  f32x16 acc;
#pragma unroll
  for (int r = 0; r < 16; ++r) acc[r] = 0.f;

  for (int kh = 0; kh < 3; ++kh) {
    const int ih = 2 * oh + kh;
    if (ih >= 64) continue;
#pragma unroll
    for (int kw = 0; kw < 3; ++kw) {
      const int p = kw & 1;
      const short* pa = xpp + ((size_t)((b * 2 + p) * 64 + ih) * 16 + cs * 4) * 512
                      + l * 8 + (kw == 2 ? 8 : 0);
      const short* pb = w3p + ((size_t)((kh * 3 + kw) * 8 + ocg) * 16 + cs * 4) * 512 + l * 8;
      const bool kill = (kw == 2) && (col == 31);
#pragma unroll
      for (int kb = 0; kb < 4; ++kb) {
        bf16x8 a = *(const bf16x8*)(pa + kb * 512);
        if (kill) a = zv;
        const bf16x8 bb = *(const bf16x8*)(pb + kb * 512);
        acc = __builtin_amdgcn_mfma_f32_32x32x16_bf16(a, bb, acc, 0, 0, 0);
      }
    }
  }
  const int half = l >> 5;
  const int oc = ocg * 32 + col;
#pragma unroll
  for (int q = 0; q < 4; ++q)
#pragma unroll
    for (int rr = 0; rr < 4; ++rr) {
      const int ow = rr + 8 * q + 4 * half;
      convp[((size_t)bz * 1024 + oh * 32 + ow) * 256 + oc] = acc[q * 4 + rr];
    }
}

// ---------- merge conv quarters + bias -> packed bf16 xdtb ----------
__global__ void k_convmerge3(const float* __restrict__ convp, const float* __restrict__ db,
                             short* __restrict__ xdtb) {
  const int i = blockIdx.x * 256 + threadIdx.x;  // 131072 groups of 4
  const int b = i >> 16, px = (i >> 6) & 1023, oc0 = (i & 63) * 4;
  const size_t base = ((size_t)px) * 256 + oc0;
  const float4 h0 = *(const float4*)(convp + ((size_t)(0 + b) << 18) + base);
  const float4 h1 = *(const float4*)(convp + ((size_t)(2 + b) << 18) + base);
  const float4 h2 = *(const float4*)(convp + ((size_t)(4 + b) << 18) + base);
  const float4 h3 = *(const float4*)(convp + ((size_t)(6 + b) << 18) + base);
  const float4 bv = *(const float4*)(db + oc0);
  short4 o;
  o.x = f2b(h0.x + h1.x + h2.x + h3.x + bv.x);
  o.y = f2b(h0.y + h1.y + h2.y + h3.y + bv.y);
  o.z = f2b(h0.z + h1.z + h2.z + h3.z + bv.z);
  o.w = f2b(h0.w + h1.w + h2.w + h3.w + bv.w);
  const size_t off = ((size_t)((b * 32 + (px >> 5)) * 16 + (oc0 >> 4)) * 2 + ((oc0 >> 3) & 1)) * 256
                   + (px & 31) * 8 + (oc0 & 7);
  *(short4*)(xdtb + off) = o;
}

// ---------- final 1x1 GEMM on packed operands, f32 out + row bias ----------
__global__ __launch_bounds__(256) void k_mfma_nt2(const short* __restrict__ woutp,
                                                  const short* __restrict__ xdtb,
                                                  float* __restrict__ C,
                                                  const float* __restrict__ bias) {
  const int b = blockIdx.z;
  xdtb += (size_t)b * 1024 * CH;
  C += (size_t)b * 512 * 1024;
  const int t = threadIdx.x, l = t & 63, wid = t >> 6;
  const int m0 = blockIdx.y * 128 + wid * 32, n0 = blockIdx.x * 64;
  const int col = l & 31, half = l >> 5;
  f32x16 acc[2];
#pragma unroll
  for (int nt = 0; nt < 2; ++nt)
#pragma unroll
    for (int r = 0; r < 16; ++r) acc[nt][r] = 0.f;
  const short* pa = woutp + (size_t)(m0 >> 5) * 8192 + l * 8;
  const short* pb = xdtb + (size_t)(n0 >> 5) * 8192 + l * 8;
#pragma unroll 4
  for (int kb = 0; kb < 16; ++kb) {
    const bf16x8 a = *(const bf16x8*)(pa + kb * 512);
    const bf16x8 b0 = *(const bf16x8*)(pb + kb * 512);
    const bf16x8 b1 = *(const bf16x8*)(pb + 8192 + kb * 512);
    acc[0] = __builtin_amdgcn_mfma_f32_32x32x16_bf16(a, b0, acc[0], 0, 0, 0);
    acc[1] = __builtin_amdgcn_mfma_f32_32x32x16_bf16(a, b1, acc[1], 0, 0, 0);
  }
#pragma unroll
  for (int nt = 0; nt < 2; ++nt) {
#pragma unroll
    for (int q = 0; q < 4; ++q)
#pragma unroll
      for (int rr = 0; rr < 4; ++rr) {
        const int row = m0 + rr + 8 * q + 4 * half;
        const int cc = n0 + nt * 32 + col;
        C[(size_t)row * 1024 + cc] = acc[nt][q * 4 + rr] + bias[row];
      }
  }
}

extern "C" void kernel_launch(void* const* d_in, const int* in_sizes, int n_in,
                              void* d_out, int out_size, void* d_ws, size_t ws_size,
                              hipStream_t stream) {
  const float* x     = (const float*)d_in[0];
  const float* fc_w  = (const float*)d_in[1];
  const float* fc_b  = (const float*)d_in[2];
  const float* gamma = (const float*)d_in[3];
  const float* beta  = (const float*)d_in[4];
  const float* dw    = (const float*)d_in[5];
  const float* db    = (const float*)d_in[6];
  const float* ow    = (const float*)d_in[7];
  const float* ob    = (const float*)d_in[8];

  float* ws   = (float*)d_ws;
  short* xp   = (short*)(ws + OFF_XP);
  float* convp= ws + OFF_XP;              // 8 MB: XP+XR (both dead after hgemm_n5)
  short* vb   = (short*)(ws + OFF_VB);
  short* tbs  = (short*)(ws + OFF_TBS);   // y^T; later xdtb
  short* xdtb = (short*)(ws + OFF_TBS);
  short* tbs2 = (short*)(ws + OFF_TBS2);  // E^T; later xpp
  short* xpp  = (short*)(ws + OFF_TBS2);
  unsigned* hg = (unsigned*)(ws + OFF_HG);
  float* sqv  = ws + OFF_SQ;
  float* part = ws + OFF_PART;
  float* bnss = ws + OFF_BNSS;
  float* dinvf= ws + OFF_DINV;
  short* w3p  = (short*)(ws + OFF_W3P);
  short* wfcp = (short*)(ws + OFF_WFCP);
  short* woutp= (short*)(ws + OFF_WOUTP);
  float* out  = (float*)d_out;

  // fused: transpose+pack+sq (256 blocks) | weight packs (3072 blocks)
  k_front2<<<3328, 256, 0, stream>>>(x, xp, sqv, fc_w, ow, dw, wfcp, woutp, w3p);
  // Gram: triangular 128x128 blocks (2 waves), writes upper + mirrored words directly
  k_gram4<<<dim3(528, 1, 2), 128, 0, stream>>>(xp, sqv, hg);
  // fused: fc GEMM (256 blocks) | 1/deg (2048 blocks)
  k_fcdinv<<<2304, 256, 0, stream>>>(wfcp, xp, tbs, fc_b, hg, dinvf);
  // E^T: XCD-pinned 1D grid, 8-wave K-split, LDS reduce + dinv
  k_hgemm_t5<<<512, 512, 0, stream>>>(tbs, hg, dinvf, tbs2);
  // v: XCD-pinned 1D grid, 8-wave K-split, LDS reduce + dinv + residual
  k_hgemm_n5<<<512, 512, 0, stream>>>(hg, tbs2, dinvf, xp, vb);
  // BN + SiLU -> conv input pack
  k_bnstat<<<128, 256, 0, stream>>>(vb, part);
  k_bnfin<<<1, 256, 0, stream>>>(part, gamma, beta, bnss);
  k_bnapply3<<<2048, 256, 0, stream>>>(vb, bnss, xpp);
  // 3x3 s2 conv (packed MFMA, K split 4-way) -> f32 partials -> packed bf16
  k_conv5<<<dim3(8, 32, 8), 64, 0, stream>>>(xpp, w3p, convp);
  k_convmerge3<<<512, 256, 0, stream>>>(convp, db, xdtb);
  // out = out_w @ xdT^T + out_b
  k_mfma_nt2<<<dim3(16, 4, 2), 256, 0, stream>>>(woutp, xdtb, out, ob);
}